// Round 1
// 1080.266 us; speedup vs baseline: 1.1701x; 1.1701x over previous
//
#include <hip/hip_runtime.h>
#include <hip/hip_bf16.h>
#include <cstdint>
#include <cstddef>

typedef __bf16 bf16x8 __attribute__((ext_vector_type(8)));
typedef float f32x4 __attribute__((ext_vector_type(4)));
using bf16_t = __hip_bfloat16;

constexpr int kHID = 1536;
constexpr int kH = 8;
constexpr int kD = 192;
constexpr int kW = 12;
constexpr int kC = 24;
constexpr int kF = 13;
constexpr int kB = 4;
constexpr int kT = 4096;
constexpr int kU = 342;        // ceil(T/W)
constexpr int kNQKV = 4608;    // 3*HID
constexpr int kM = kB * kT;    // 16384
constexpr int kKV = 2 * kHID;  // 3072

// ws layout (bytes): [kv bf16][wt bf16][sinb f32][hsb bf16]
constexpr size_t kKvBytes = (size_t)kM * kKV * 2;      // 100,663,296
constexpr size_t kWtBytes = (size_t)kNQKV * kHID * 2;  // 14,155,776
constexpr size_t kSinBytes = (size_t)kF * kHID * 4;    // 79,872
constexpr size_t kHsbBytes = (size_t)kM * kHID * 2;    // 50,331,648
constexpr size_t kWtOff = kKvBytes;
constexpr size_t kSinOff = kWtOff + kWtBytes;
constexpr size_t kHsbOff = kSinOff + kSinBytes;
constexpr size_t kWsNeed = kHsbOff + kHsbBytes;        // ~165.2 MB

// async global->LDS, 16 bytes per lane (global_load_lds_dwordx4)
__device__ __forceinline__ void load_lds16(const bf16_t* g, bf16_t* l) {
  __builtin_amdgcn_global_load_lds(
      (const __attribute__((address_space(1))) void*)g,
      (__attribute__((address_space(3))) void*)l, 16, 0, 0);
}

// ---------------------------------------------------------------------------
// Kernel 1: transpose + concat weights (fp32 in) -> wt[n][k] (bf16)
// ---------------------------------------------------------------------------
__global__ __launch_bounds__(256) void transpose_w(const float* __restrict__ wq,
                                                   const float* __restrict__ wk,
                                                   const float* __restrict__ wv,
                                                   bf16_t* __restrict__ wt) {
  __shared__ bf16_t tile[32][33];
  const int s = blockIdx.z;
  const float* w = (s == 0) ? wq : (s == 1) ? wk : wv;
  const int k0 = blockIdx.x * 32, n0 = blockIdx.y * 32;
  for (int i = threadIdx.y; i < 32; i += 8)
    tile[i][threadIdx.x] = (bf16_t)w[(size_t)(k0 + i) * kHID + n0 + threadIdx.x];
  __syncthreads();
  for (int i = threadIdx.y; i < 32; i += 8)
    wt[(size_t)(s * kHID + n0 + i) * kHID + k0 + threadIdx.x] = tile[threadIdx.x][i];
}

// ---------------------------------------------------------------------------
// Kernel 1b: hs fp32 -> bf16 (amortize conversion once instead of 36x in GEMM,
// and halve GEMM A-operand fetch bytes)
// ---------------------------------------------------------------------------
__global__ __launch_bounds__(256) void convert_hs(const float* __restrict__ hs,
                                                  bf16_t* __restrict__ hsb) {
  const size_t total = (size_t)kM * kHID;  // 25,165,824 (multiple of 8)
  const size_t stride = (size_t)gridDim.x * 256 * 8;
  for (size_t i = ((size_t)blockIdx.x * 256 + threadIdx.x) * 8; i < total; i += stride) {
    f32x4 a = *(const f32x4*)(hs + i);
    f32x4 b = *(const f32x4*)(hs + i + 4);
    bf16x8 o;
#pragma unroll
    for (int e = 0; e < 4; e++) { o[e] = (__bf16)a[e]; o[e + 4] = (__bf16)b[e]; }
    *(bf16x8*)(hsb + i) = o;
  }
}

// ---------------------------------------------------------------------------
// Kernel 2: sin_emb[f][n] = timing_signal(pos)[f] @ w_pos  (fp32 in/out)
// ---------------------------------------------------------------------------
__global__ __launch_bounds__(256) void sinemb_kernel(const float* __restrict__ w_pos,
                                                     float* __restrict__ sinb) {
  __shared__ float ts[kHID];
  const int f = blockIdx.y;
  const int n = blockIdx.x * 256 + threadIdx.x;
  const float pos = (float)(12 - f);  // pos[f] = MAX_PAST - f, MAX_FUT = 0
  const float log_inc = logf(10000.0f) / 767.0f;
  for (int j = threadIdx.x; j < 768; j += 256) {
    float inv = expf(-(float)j * log_inc);
    float a = pos * inv;
    ts[j] = sinf(a);
    ts[768 + j] = cosf(a);
  }
  __syncthreads();
  float acc = 0.0f;
  for (int m = 0; m < kHID; m++) acc += ts[m] * w_pos[(size_t)m * kHID + n];
  sinb[f * kHID + n] = acc;
}

// ---------------------------------------------------------------------------
// Kernel 3: QKV GEMM, m97 structure: 128x128 tile, BK=32, 4 waves,
// global_load_lds width=16 for both operands, 2 barriers per K-step.
// [M=16384][N=4608] = hsb[M][1536](bf16) @ wt[N][1536]^T
// q-cols (n<1536) -> d_out (fp32); k/v-cols -> kv ws buffer (bf16).
// ---------------------------------------------------------------------------
__global__ __launch_bounds__(256) void gemm_qkv(const bf16_t* __restrict__ hsb,
                                                const bf16_t* __restrict__ wt,
                                                float* __restrict__ qout,
                                                bf16_t* __restrict__ kvout) {
  __shared__ bf16_t As[128 * 32];
  __shared__ bf16_t Bs[128 * 32];
  const int tid = threadIdx.x;
  const int lane = tid & 63, wid = tid >> 6;
  const int t0 = blockIdx.y * 128, n0 = blockIdx.x * 128;
  const int mb = lane & 15, quad = lane >> 4;
  const int wrow = (wid >> 1) * 64, wcol = (wid & 1) * 64;

  f32x4 acc[4][4] = {};

  // 16B chunk c in [0,512): row c>>2, k-offset (c&3)*8; LDS elem offset c*8.
  // Chunk id == tid (+256) => LDS dest is wave-uniform base + lane*16 (G::load req).
  const int c0 = tid, c1 = tid + 256;
  const bf16_t* a0 = hsb + (size_t)(t0 + (c0 >> 2)) * kHID + (c0 & 3) * 8;
  const bf16_t* a1 = hsb + (size_t)(t0 + (c1 >> 2)) * kHID + (c1 & 3) * 8;
  const bf16_t* b0 = wt + (size_t)(n0 + (c0 >> 2)) * kHID + (c0 & 3) * 8;
  const bf16_t* b1 = wt + (size_t)(n0 + (c1 >> 2)) * kHID + (c1 & 3) * 8;
  bf16_t* lA0 = &As[c0 * 8];
  bf16_t* lA1 = &As[c1 * 8];
  bf16_t* lB0 = &Bs[c0 * 8];
  bf16_t* lB1 = &Bs[c1 * 8];

  for (int k0 = 0; k0 < kHID; k0 += 32) {
    __syncthreads();  // previous tile's LDS reads complete (lgkmcnt drained)
    load_lds16(a0, lA0);
    load_lds16(a1, lA1);
    load_lds16(b0, lB0);
    load_lds16(b1, lB1);
    a0 += 32; a1 += 32; b0 += 32; b1 += 32;
    __syncthreads();  // vmcnt(0) drained before barrier => tile resident

    bf16x8 af[4], bg[4];
#pragma unroll
    for (int i = 0; i < 4; i++)
      af[i] = *(const bf16x8*)(&As[(wrow + i * 16 + mb) * 32 + quad * 8]);
#pragma unroll
    for (int j = 0; j < 4; j++)
      bg[j] = *(const bf16x8*)(&Bs[(wcol + j * 16 + mb) * 32 + quad * 8]);
#pragma unroll
    for (int i = 0; i < 4; i++)
#pragma unroll
      for (int j = 0; j < 4; j++)
        acc[i][j] = __builtin_amdgcn_mfma_f32_16x16x32_bf16(af[i], bg[j], acc[i][j], 0, 0, 0);
  }

  // epilogue: C/D layout col=lane&15 (N side), row=quad*4+reg (M side)
  const bool isq = (n0 < kHID);  // block-uniform
#pragma unroll
  for (int i = 0; i < 4; i++)
#pragma unroll
    for (int j = 0; j < 4; j++)
#pragma unroll
      for (int r = 0; r < 4; r++) {
        int row = t0 + wrow + i * 16 + quad * 4 + r;
        int col = wcol + j * 16 + mb;
        if (isq) {
          qout[(size_t)row * kHID + n0 + col] = acc[i][j][r];
        } else {
          kvout[(size_t)row * kKV + (n0 - kHID) + col] = (bf16_t)acc[i][j][r];
        }
      }
}

// ---------------------------------------------------------------------------
// Kernel 4: local relative attention. grid (U, B, H), block 256. (unchanged)
// ---------------------------------------------------------------------------
__global__ __launch_bounds__(256) void attn_kernel(const bf16_t* __restrict__ kv,
                                                   const unsigned char* __restrict__ mask,
                                                   const float* __restrict__ sinb,
                                                   const float* __restrict__ pds,
                                                   float* __restrict__ out) {
  const int u = blockIdx.x, b = blockIdx.y, h = blockIdx.z;
  const int tid = threadIdx.x;

  __shared__ float qs[kW][kD + 1];
  __shared__ float ks[kC][kD + 1];
  __shared__ float vs[kC][kD + 1];
  __shared__ float sins[kF][kD + 1];
  __shared__ float lg[kW][kC + 1];
  __shared__ float ss[kD];
  __shared__ int validc[kC];

  if (tid < kD) {
    float p = pds[tid];
    float sp = log1pf(expf(p));  // softplus
    ss[tid] = (1.0f / (sqrtf(192.0f) * logf(2.0f))) * sp;
  }
  if (tid < kC) {
    int p = u * kW + tid - 12;
    validc[tid] = (p >= 0 && p < kT && mask[b * kT + p] == 0) ? 1 : 0;
  }
  __syncthreads();

  for (int i = tid; i < kW * kD; i += 256) {
    int w = i / kD, d = i % kD;
    int t = u * kW + w;
    float v = 0.0f;
    if (t < kT) v = out[((size_t)(b * kT + t)) * kHID + h * kD + d] * ss[d];
    qs[w][d] = v;
  }
  for (int i = tid; i < kC * kD; i += 256) {
    int c = i / kD, d = i % kD;
    int p = u * kW + c - 12;
    float kval = 0.0f, vval = 0.0f;
    if (p >= 0 && p < kT) {
      size_t base = (size_t)(b * kT + p) * kKV;
      kval = (float)kv[base + h * kD + d];
      vval = (float)kv[base + kHID + h * kD + d];
    }
    ks[c][d] = kval;
    vs[c][d] = vval;
  }
  for (int i = tid; i < kF * kD; i += 256) {
    int f = i / kD, d = i % kD;
    sins[f][d] = sinb[f * kHID + h * kD + d];
  }
  __syncthreads();

  // logits (tanh soft-cap then mask)
  for (int i = tid; i < kW * kC; i += 256) {
    int w = i / kC, c = i % kC;
    float l = -3.4028234663852886e38f;
    int f = c - w;
    if (f >= 0 && f <= 12 && validc[c]) {
      float ac = 0.0f, bd = 0.0f;
      for (int d = 0; d < kD; d++) {
        float q = qs[w][d];
        ac += q * ks[c][d];
        bd += q * sins[f][d];
      }
      l = tanhf((ac + bd) * (1.0f / 50.0f)) * 50.0f;
    }
    lg[w][c] = l;
  }
  __syncthreads();

  // softmax per query row
  if (tid < kW) {
    float m = -3.4028234663852886e38f;
#pragma unroll
    for (int c = 0; c < kC; c++) m = fmaxf(m, lg[tid][c]);
    float e[kC];
    float s = 0.0f;
#pragma unroll
    for (int c = 0; c < kC; c++) {
      float ex = expf(lg[tid][c] - m);
      e[c] = ex;
      s += ex;
    }
    float inv = 1.0f / s;
#pragma unroll
    for (int c = 0; c < kC; c++) lg[tid][c] = e[c] * inv;
  }
  __syncthreads();

  // ctx = probs @ V (probs exactly 0 outside band [w, w+12])
  for (int i = tid; i < kW * kD; i += 256) {
    int w = i / kD, d = i % kD;
    int t = u * kW + w;
    if (t >= kT) continue;
    float acc = 0.0f;
#pragma unroll
    for (int c = 0; c < 13; c++) acc += lg[w][w + c] * vs[w + c][d];
    out[((size_t)(b * kT + t)) * kHID + h * kD + d] = acc;
  }
}

// ---------------------------------------------------------------------------
extern "C" void kernel_launch(void* const* d_in, const int* in_sizes, int n_in,
                              void* d_out, int out_size, void* d_ws, size_t ws_size,
                              hipStream_t stream) {
  if (ws_size < kWsNeed) return;  // beacon: absmax == 3.92 means ws too small

  const float* hs = (const float*)d_in[0];
  const unsigned char* mask = (const unsigned char*)d_in[1];
  const float* wq = (const float*)d_in[2];
  const float* wk = (const float*)d_in[3];
  const float* wv = (const float*)d_in[4];
  const float* wpos = (const float*)d_in[5];
  const float* pds = (const float*)d_in[6];
  float* out = (float*)d_out;

  char* ws = (char*)d_ws;
  bf16_t* kv = (bf16_t*)ws;
  bf16_t* wt = (bf16_t*)(ws + kWtOff);
  float* sinb = (float*)(ws + kSinOff);
  bf16_t* hsb = (bf16_t*)(ws + kHsbOff);

  transpose_w<<<dim3(48, 48, 3), dim3(32, 8), 0, stream>>>(wq, wk, wv, wt);
  convert_hs<<<dim3(2048), 256, 0, stream>>>(hs, hsb);
  sinemb_kernel<<<dim3(6, 13), 256, 0, stream>>>(wpos, sinb);
  gemm_qkv<<<dim3(kNQKV / 128, kM / 128), 256, 0, stream>>>(hsb, wt, out, kv);
  attn_kernel<<<dim3(kU, kB, kH), 256, 0, stream>>>(kv, mask, sinb, pds, out);
}

// Round 2
// 611.672 us; speedup vs baseline: 2.0665x; 1.7661x over previous
//
#include <hip/hip_runtime.h>
#include <hip/hip_bf16.h>
#include <cstdint>
#include <cstddef>

typedef __bf16 bf16x8 __attribute__((ext_vector_type(8)));
typedef __bf16 bf16x4_t __attribute__((ext_vector_type(4)));
typedef float f32x4 __attribute__((ext_vector_type(4)));
using bf16_t = __hip_bfloat16;

constexpr int kHID = 1536;
constexpr int kH = 8;
constexpr int kD = 192;
constexpr int kW = 12;
constexpr int kC = 24;
constexpr int kF = 13;
constexpr int kB = 4;
constexpr int kT = 4096;
constexpr int kU = 342;        // ceil(T/W)
constexpr int kNQKV = 4608;    // 3*HID
constexpr int kM = kB * kT;    // 16384
constexpr int kKV = 2 * kHID;  // 3072 (old interleaved layout)

// ws layout (bytes):
//   [0)            kvK   : big mode = K rows [16384][1536] bf16 (50,331,648)
//   [kVtOff)       vtws  : big mode = V^T [1536(h*192+d)][16384] bf16 (50,331,648)
//                  (small mode: bytes [0, 100663296) = old interleaved kv [row][3072])
//   [kWtOff)       wt    : [4608][1536] bf16
//   [kSinOff)      sinb  : [13][1536] f32
//   [kSinBfOff)    sinbf : [16][1536] bf16 (rows 13..15 zeroed)
//   [kSsOff)       ssb   : [192] f32 (padded to 1024)
//   [kHsbOff)      hsb   : [16384][1536] bf16
//   [kQbOff)       qb    : [16384][1536] bf16 (big mode only; scaled Q)
constexpr size_t kVtOff = 50331648;
constexpr size_t kWtOff = 100663296;
constexpr size_t kSinOff = kWtOff + (size_t)kNQKV * kHID * 2;      // 114819072
constexpr size_t kSinBfOff = kSinOff + (size_t)kF * kHID * 4;      // +79872
constexpr size_t kSsOff = kSinBfOff + (size_t)16 * kHID * 2;       // +49152
constexpr size_t kHsbOff = kSsOff + 1024;
constexpr size_t kQbOff = kHsbOff + (size_t)kM * kHID * 2;
constexpr size_t kWsNeedSmall = kQbOff;                             // 165,280,768
constexpr size_t kWsNeedBig = kQbOff + (size_t)kM * kHID * 2;       // 215,612,416

// async global->LDS, 16 bytes per lane (global_load_lds_dwordx4)
__device__ __forceinline__ void load_lds16(const void* g, void* l) {
  __builtin_amdgcn_global_load_lds(
      (const __attribute__((address_space(1))) void*)g,
      (__attribute__((address_space(3))) void*)l, 16, 0, 0);
}

// ---------------------------------------------------------------------------
// Kernel 1: transpose + concat weights (fp32 in) -> wt[n][k] (bf16)
// ---------------------------------------------------------------------------
__global__ __launch_bounds__(256) void transpose_w(const float* __restrict__ wq,
                                                   const float* __restrict__ wk,
                                                   const float* __restrict__ wv,
                                                   bf16_t* __restrict__ wt) {
  __shared__ bf16_t tile[32][33];
  const int s = blockIdx.z;
  const float* w = (s == 0) ? wq : (s == 1) ? wk : wv;
  const int k0 = blockIdx.x * 32, n0 = blockIdx.y * 32;
  for (int i = threadIdx.y; i < 32; i += 8)
    tile[i][threadIdx.x] = (bf16_t)w[(size_t)(k0 + i) * kHID + n0 + threadIdx.x];
  __syncthreads();
  for (int i = threadIdx.y; i < 32; i += 8)
    wt[(size_t)(s * kHID + n0 + i) * kHID + k0 + threadIdx.x] = tile[threadIdx.x][i];
}

// ---------------------------------------------------------------------------
// Kernel 1b: hs fp32 -> bf16
// ---------------------------------------------------------------------------
__global__ __launch_bounds__(256) void convert_hs(const float* __restrict__ hs,
                                                  bf16_t* __restrict__ hsb) {
  const size_t total = (size_t)kM * kHID;
  const size_t stride = (size_t)gridDim.x * 256 * 8;
  for (size_t i = ((size_t)blockIdx.x * 256 + threadIdx.x) * 8; i < total; i += stride) {
    f32x4 a = *(const f32x4*)(hs + i);
    f32x4 b = *(const f32x4*)(hs + i + 4);
    bf16x8 o;
#pragma unroll
    for (int e = 0; e < 4; e++) { o[e] = (__bf16)a[e]; o[e + 4] = (__bf16)b[e]; }
    *(bf16x8*)(hsb + i) = o;
  }
}

// ---------------------------------------------------------------------------
// Kernel 2: sin_emb[f][n] = timing_signal(pos)[f] @ w_pos  (f32 + bf16 out)
// ---------------------------------------------------------------------------
__global__ __launch_bounds__(256) void sinemb_kernel(const float* __restrict__ w_pos,
                                                     float* __restrict__ sinb,
                                                     bf16_t* __restrict__ sinbf) {
  __shared__ float ts[kHID];
  const int f = blockIdx.y;
  const int n = blockIdx.x * 256 + threadIdx.x;
  const float pos = (float)(12 - f);
  const float log_inc = logf(10000.0f) / 767.0f;
  for (int j = threadIdx.x; j < 768; j += 256) {
    float inv = expf(-(float)j * log_inc);
    float a = pos * inv;
    ts[j] = sinf(a);
    ts[768 + j] = cosf(a);
  }
  __syncthreads();
  float acc = 0.0f;
  for (int m = 0; m < kHID; m++) acc += ts[m] * w_pos[(size_t)m * kHID + n];
  sinb[f * kHID + n] = acc;
  sinbf[f * kHID + n] = (bf16_t)acc;
  if (f == 0) {  // zero pad rows 13..15 (avoid NaN garbage feeding MFMA)
    sinbf[13 * kHID + n] = (bf16_t)0.0f;
    sinbf[14 * kHID + n] = (bf16_t)0.0f;
    sinbf[15 * kHID + n] = (bf16_t)0.0f;
  }
}

// ---------------------------------------------------------------------------
// Kernel 2b: ss[d] = D^-0.5/ln2 * softplus(pds[d])
// ---------------------------------------------------------------------------
__global__ void compute_ss(const float* __restrict__ pds, float* __restrict__ ssb) {
  int d = threadIdx.x;
  if (d < kD) {
    float p = pds[d];
    float sp = log1pf(expf(p));
    ssb[d] = (1.0f / (sqrtf(192.0f) * logf(2.0f))) * sp;
  }
}

// ---------------------------------------------------------------------------
// Kernel 3: QKV GEMM (m97 structure). MODE 0: q->out f32, kv interleaved.
// MODE 1: q->qb bf16 scaled by ss[d]; K->kvK [row][1536]; V->vtws transposed.
// ---------------------------------------------------------------------------
template <int MODE>
__global__ __launch_bounds__(256) void gemm_qkv_t(const bf16_t* __restrict__ hsb,
                                                  const bf16_t* __restrict__ wt,
                                                  float* __restrict__ qout,
                                                  bf16_t* __restrict__ kvout,
                                                  bf16_t* __restrict__ vtws,
                                                  bf16_t* __restrict__ qbout,
                                                  const float* __restrict__ ssb) {
  __shared__ bf16_t As[128 * 32];
  __shared__ bf16_t Bs[128 * 32];
  const int tid = threadIdx.x;
  const int lane = tid & 63, wid = tid >> 6;
  const int t0 = blockIdx.y * 128, n0 = blockIdx.x * 128;
  const int mb = lane & 15, quad = lane >> 4;
  const int wrow = (wid >> 1) * 64, wcol = (wid & 1) * 64;

  f32x4 acc[4][4] = {};

  const int c0 = tid, c1 = tid + 256;
  const bf16_t* a0 = hsb + (size_t)(t0 + (c0 >> 2)) * kHID + (c0 & 3) * 8;
  const bf16_t* a1 = hsb + (size_t)(t0 + (c1 >> 2)) * kHID + (c1 & 3) * 8;
  const bf16_t* b0 = wt + (size_t)(n0 + (c0 >> 2)) * kHID + (c0 & 3) * 8;
  const bf16_t* b1 = wt + (size_t)(n0 + (c1 >> 2)) * kHID + (c1 & 3) * 8;
  bf16_t* lA0 = &As[c0 * 8];
  bf16_t* lA1 = &As[c1 * 8];
  bf16_t* lB0 = &Bs[c0 * 8];
  bf16_t* lB1 = &Bs[c1 * 8];

  for (int k0 = 0; k0 < kHID; k0 += 32) {
    __syncthreads();
    load_lds16(a0, lA0);
    load_lds16(a1, lA1);
    load_lds16(b0, lB0);
    load_lds16(b1, lB1);
    a0 += 32; a1 += 32; b0 += 32; b1 += 32;
    __syncthreads();

    bf16x8 af[4], bg[4];
#pragma unroll
    for (int i = 0; i < 4; i++)
      af[i] = *(const bf16x8*)(&As[(wrow + i * 16 + mb) * 32 + quad * 8]);
#pragma unroll
    for (int j = 0; j < 4; j++)
      bg[j] = *(const bf16x8*)(&Bs[(wcol + j * 16 + mb) * 32 + quad * 8]);
#pragma unroll
    for (int i = 0; i < 4; i++)
#pragma unroll
      for (int j = 0; j < 4; j++)
        acc[i][j] = __builtin_amdgcn_mfma_f32_16x16x32_bf16(af[i], bg[j], acc[i][j], 0, 0, 0);
  }

  if constexpr (MODE == 0) {
    const bool isq = (n0 < kHID);
#pragma unroll
    for (int i = 0; i < 4; i++)
#pragma unroll
      for (int j = 0; j < 4; j++)
#pragma unroll
        for (int r = 0; r < 4; r++) {
          int row = t0 + wrow + i * 16 + quad * 4 + r;
          int col = wcol + j * 16 + mb;
          if (isq) {
            qout[(size_t)row * kHID + n0 + col] = acc[i][j][r];
          } else {
            kvout[(size_t)row * kKV + (n0 - kHID) + col] = (bf16_t)acc[i][j][r];
          }
        }
  } else {
    if (n0 < kHID) {  // Q: scale by ss[d], bf16
#pragma unroll
      for (int j = 0; j < 4; j++) {
        int colj = n0 + wcol + j * 16 + mb;
        float ssv = ssb[colj % kD];
#pragma unroll
        for (int i = 0; i < 4; i++)
#pragma unroll
          for (int r = 0; r < 4; r++) {
            int row = t0 + wrow + i * 16 + quad * 4 + r;
            qbout[(size_t)row * kHID + colj] = (bf16_t)(acc[i][j][r] * ssv);
          }
      }
    } else if (n0 < 2 * kHID) {  // K rows
#pragma unroll
      for (int i = 0; i < 4; i++)
#pragma unroll
        for (int j = 0; j < 4; j++)
#pragma unroll
          for (int r = 0; r < 4; r++) {
            int row = t0 + wrow + i * 16 + quad * 4 + r;
            int col = (n0 - kHID) + wcol + j * 16 + mb;
            kvout[(size_t)row * kHID + col] = (bf16_t)acc[i][j][r];
          }
    } else {  // V transposed: vtws[vcol][row], 4 rows packed per 8B store
#pragma unroll
      for (int i = 0; i < 4; i++)
#pragma unroll
        for (int j = 0; j < 4; j++) {
          int vcol = (n0 - 2 * kHID) + wcol + j * 16 + mb;
          int row = t0 + wrow + i * 16 + quad * 4;
          bf16x4_t vv;
#pragma unroll
          for (int r = 0; r < 4; r++) vv[r] = (__bf16)acc[i][j][r];
          *(bf16x4_t*)(vtws + (size_t)vcol * kM + row) = vv;
        }
    }
  }
}

// ---------------------------------------------------------------------------
// Kernel 4 (big-ws): MFMA local relative attention.
// grid (86, B, H), block 256 = 4 waves; wave wv handles chunk u = 4*g + wv.
// Block K/V rows r = 0..67 <-> t = tb + r, tb = 48g - 12.
// QK^T swapped: D[c][w] via mfma(Kfrag, Qfrag); softmax in-reg (shfl 16/32);
// PV: D[w][d] via mfma(Pfrag, Vtfrag).
// ---------------------------------------------------------------------------
__global__ __launch_bounds__(256) void attn_mfma(const bf16_t* __restrict__ kvK,
                                                 const bf16_t* __restrict__ vtws,
                                                 const unsigned char* __restrict__ mask,
                                                 const bf16_t* __restrict__ sinbf,
                                                 const bf16_t* __restrict__ qb,
                                                 float* __restrict__ out) {
  const int g = blockIdx.x, b = blockIdx.y, h = blockIdx.z;
  const int tid = threadIdx.x;
  const int lane = tid & 63, wv = tid >> 6;
  const int w = lane & 15, quad = lane >> 4;
  const int tb = g * 48 - 12;
  const int u = g * 4 + wv;

  __shared__ bf16_t Ks[68 * 192];                  // 26112 B, 384B rows, XOR-swz
  __shared__ bf16_t Vt[192 * 80];                  // 30720 B, [d][c_lds], c_lds=c+4
  __shared__ __align__(16) char scr[4][1280];      // per-wave: bdl f32[16][16] then Pl bf16[16][40]
  __shared__ int vld[68];

  float* bdl = (float*)scr[wv];
  bf16_t* Pl = (bf16_t*)scr[wv];

  // --- Q and sins fragments (direct global, issued before staging) ---
  int tq = u * kW + w;
  int qrow = (u < kU && tq < kT) ? (b * kT + tq) : (b * kT);
  const bf16_t* qptr = qb + (size_t)qrow * kHID + h * kD + quad * 8;
  const bf16_t* sptr = sinbf + (size_t)w * kHID + h * kD + quad * 8;
  bf16x8 qf[6], sf[6];
#pragma unroll
  for (int ks = 0; ks < 6; ks++) {
    qf[ks] = *(const bf16x8*)(qptr + ks * 32);
    sf[ks] = *(const bf16x8*)(sptr + ks * 32);
  }

  // --- validity of block rows ---
  if (tid < 68) {
    int p = tb + tid;
    vld[tid] = (p >= 0 && p < kT && mask[b * kT + p] == 0) ? 1 : 0;
  }

  // --- stage K: 68 rows x 24 chunks = 1632; swizzle chunk within 128B group ---
  const char* kvb = (const char*)kvK;
#pragma unroll
  for (int it = 0; it < 7; it++) {
    int i = it * 256 + tid;
    if (i >= 1632) i -= 1632;  // duplicate-redo keeps waves full (exec-safe glds)
    int r = i / 24, cb = (i % 24) * 16;
    int row = b * kT + tb + r;
    row = row < 0 ? 0 : (row > kM - 1 ? kM - 1 : row);
    const char* src = kvb + (size_t)row * 3072 + h * 384 + (cb ^ ((r & 7) << 4));
    load_lds16(src, (char*)Ks + i * 16);
  }
  // --- stage Vt: 192 d-rows x 10 chunks (80 elems, c_lds origin = tb-4) ---
  const char* vtb = (const char*)vtws;
#pragma unroll
  for (int it = 0; it < 8; it++) {
    int i = it * 256 + tid;
    if (i >= 1920) i -= 1920;
    int d = i / 10, j = i % 10;
    int e = b * kT + tb - 4 + j * 8;
    e = e < 0 ? 0 : (e > kM - 8 ? kM - 8 : e);
    const char* src = vtb + ((size_t)(h * kD + d) * kM + e) * 2;
    load_lds16(src, (char*)Vt + i * 16);
  }
  __syncthreads();

  // --- QK^T + position term ---
  f32x4 ac0 = {0.f, 0.f, 0.f, 0.f}, ac1 = {0.f, 0.f, 0.f, 0.f}, bdv = {0.f, 0.f, 0.f, 0.f};
  const int r0 = wv * kW + w;   // A-row for c-tile0 (block-local)
  const int r1 = r0 + 16;       // c-tile1
#pragma unroll
  for (int ks = 0; ks < 6; ks++) {
    int kb = ks * 64 + quad * 16;
    bf16x8 ka0 = *(const bf16x8*)((const char*)Ks + (size_t)r0 * 384 + (kb ^ ((r0 & 7) << 4)));
    bf16x8 ka1 = *(const bf16x8*)((const char*)Ks + (size_t)r1 * 384 + (kb ^ ((r1 & 7) << 4)));
    ac0 = __builtin_amdgcn_mfma_f32_16x16x32_bf16(ka0, qf[ks], ac0, 0, 0, 0);
    ac1 = __builtin_amdgcn_mfma_f32_16x16x32_bf16(ka1, qf[ks], ac1, 0, 0, 0);
    bdv = __builtin_amdgcn_mfma_f32_16x16x32_bf16(sf[ks], qf[ks], bdv, 0, 0, 0);
  }

  // bd (D[f][w]) -> per-wave LDS so same-w lanes can fetch f = c - w
  *(f32x4*)&bdl[w * 16 + quad * 4] = bdv;
  asm volatile("s_waitcnt lgkmcnt(0)" ::: "memory");

  // --- logits (tanh soft-cap, mask) ---
  float l[8];
#pragma unroll
  for (int T = 0; T < 2; T++)
#pragma unroll
    for (int r = 0; r < 4; r++) {
      int c = T * 16 + quad * 4 + r;
      int f = c - w;
      int fr = f < 0 ? 0 : (f > 15 ? 15 : f);
      float a = T ? ac1[r] : ac0[r];
      float bb = bdl[w * 16 + fr];
      bool val = (f >= 0) && (f <= 12) && (c < kC) && (vld[wv * kW + c] != 0);
      float x2 = (a + bb) * 0.04f;  // 2x/50
      float ee = __expf(x2);
      float th = (ee - 1.0f) * __builtin_amdgcn_rcpf(ee + 1.0f);
      l[T * 4 + r] = val ? 50.0f * th : -3.4028234663852886e38f;
    }

  // --- softmax across the 4 lanes sharing w (quads) ---
  float m = l[0];
#pragma unroll
  for (int k = 1; k < 8; k++) m = fmaxf(m, l[k]);
  m = fmaxf(m, __shfl_xor(m, 16, 64));
  m = fmaxf(m, __shfl_xor(m, 32, 64));
  float e8[8], s = 0.0f;
#pragma unroll
  for (int k = 0; k < 8; k++) { e8[k] = __expf(l[k] - m); s += e8[k]; }
  s += __shfl_xor(s, 16, 64);
  s += __shfl_xor(s, 32, 64);
  float inv = 1.0f / s;

  // --- probs -> bf16 into Pl (c>=24 pad written as exact 0) ---
#pragma unroll
  for (int T = 0; T < 2; T++) {
    bf16x4_t pk;
#pragma unroll
    for (int r = 0; r < 4; r++) {
      int c = T * 16 + quad * 4 + r;
      float p = (c < kC) ? e8[T * 4 + r] * inv : 0.0f;
      pk[r] = (__bf16)p;
    }
    *(bf16x4_t*)&Pl[w * 40 + T * 16 + quad * 4] = pk;
  }
  asm volatile("s_waitcnt lgkmcnt(0)" ::: "memory");
  __builtin_amdgcn_sched_barrier(0);

  // --- PV: D[w][d] = mfma(P, Vt) per 16-col d-tile ---
  bf16x8 pa = *(const bf16x8*)&Pl[w * 40 + quad * 8];
  const int cl0 = 4 + wv * kW + quad * 8;
  const bool uok = (u < kU);
#pragma unroll
  for (int T = 0; T < 12; T++) {
    bf16x4_t v0 = *(const bf16x4_t*)&Vt[(T * 16 + w) * 80 + cl0];
    bf16x4_t v1 = *(const bf16x4_t*)&Vt[(T * 16 + w) * 80 + cl0 + 4];
    bf16x8 vf;
#pragma unroll
    for (int e2 = 0; e2 < 4; e2++) { vf[e2] = v0[e2]; vf[e2 + 4] = v1[e2]; }
    f32x4 oz = {0.f, 0.f, 0.f, 0.f};
    oz = __builtin_amdgcn_mfma_f32_16x16x32_bf16(pa, vf, oz, 0, 0, 0);
    if (uok) {
#pragma unroll
      for (int r = 0; r < 4; r++) {
        int wr = quad * 4 + r;
        int t = u * kW + wr;
        if (wr < kW && t < kT)
          out[((size_t)(b * kT + t)) * kHID + h * kD + T * 16 + w] = oz[r];
      }
    }
  }
}

// ---------------------------------------------------------------------------
// Kernel 4 (fallback, small ws): round-1 scalar attention (unchanged).
// ---------------------------------------------------------------------------
__global__ __launch_bounds__(256) void attn_kernel(const bf16_t* __restrict__ kv,
                                                   const unsigned char* __restrict__ mask,
                                                   const float* __restrict__ sinb,
                                                   const float* __restrict__ pds,
                                                   float* __restrict__ out) {
  const int u = blockIdx.x, b = blockIdx.y, h = blockIdx.z;
  const int tid = threadIdx.x;

  __shared__ float qs[kW][kD + 1];
  __shared__ float ks[kC][kD + 1];
  __shared__ float vs[kC][kD + 1];
  __shared__ float sins[kF][kD + 1];
  __shared__ float lg[kW][kC + 1];
  __shared__ float ss[kD];
  __shared__ int validc[kC];

  if (tid < kD) {
    float p = pds[tid];
    float sp = log1pf(expf(p));
    ss[tid] = (1.0f / (sqrtf(192.0f) * logf(2.0f))) * sp;
  }
  if (tid < kC) {
    int p = u * kW + tid - 12;
    validc[tid] = (p >= 0 && p < kT && mask[b * kT + p] == 0) ? 1 : 0;
  }
  __syncthreads();

  for (int i = tid; i < kW * kD; i += 256) {
    int w = i / kD, d = i % kD;
    int t = u * kW + w;
    float v = 0.0f;
    if (t < kT) v = out[((size_t)(b * kT + t)) * kHID + h * kD + d] * ss[d];
    qs[w][d] = v;
  }
  for (int i = tid; i < kC * kD; i += 256) {
    int c = i / kD, d = i % kD;
    int p = u * kW + c - 12;
    float kval = 0.0f, vval = 0.0f;
    if (p >= 0 && p < kT) {
      size_t base = (size_t)(b * kT + p) * kKV;
      kval = (float)kv[base + h * kD + d];
      vval = (float)kv[base + kHID + h * kD + d];
    }
    ks[c][d] = kval;
    vs[c][d] = vval;
  }
  for (int i = tid; i < kF * kD; i += 256) {
    int f = i / kD, d = i % kD;
    sins[f][d] = sinb[f * kHID + h * kD + d];
  }
  __syncthreads();

  for (int i = tid; i < kW * kC; i += 256) {
    int w = i / kC, c = i % kC;
    float l = -3.4028234663852886e38f;
    int f = c - w;
    if (f >= 0 && f <= 12 && validc[c]) {
      float ac = 0.0f, bd = 0.0f;
      for (int d = 0; d < kD; d++) {
        float q = qs[w][d];
        ac += q * ks[c][d];
        bd += q * sins[f][d];
      }
      l = tanhf((ac + bd) * (1.0f / 50.0f)) * 50.0f;
    }
    lg[w][c] = l;
  }
  __syncthreads();

  if (tid < kW) {
    float m = -3.4028234663852886e38f;
#pragma unroll
    for (int c = 0; c < kC; c++) m = fmaxf(m, lg[tid][c]);
    float e[kC];
    float s = 0.0f;
#pragma unroll
    for (int c = 0; c < kC; c++) {
      float ex = expf(lg[tid][c] - m);
      e[c] = ex;
      s += ex;
    }
    float inv = 1.0f / s;
#pragma unroll
    for (int c = 0; c < kC; c++) lg[tid][c] = e[c] * inv;
  }
  __syncthreads();

  for (int i = tid; i < kW * kD; i += 256) {
    int w = i / kD, d = i % kD;
    int t = u * kW + w;
    if (t >= kT) continue;
    float acc = 0.0f;
#pragma unroll
    for (int c = 0; c < 13; c++) acc += lg[w][w + c] * vs[w + c][d];
    out[((size_t)(b * kT + t)) * kHID + h * kD + d] = acc;
  }
}

// ---------------------------------------------------------------------------
extern "C" void kernel_launch(void* const* d_in, const int* in_sizes, int n_in,
                              void* d_out, int out_size, void* d_ws, size_t ws_size,
                              hipStream_t stream) {
  if (ws_size < kWsNeedSmall) return;  // beacon: absmax == 3.92 means ws too small

  const float* hs = (const float*)d_in[0];
  const unsigned char* mask = (const unsigned char*)d_in[1];
  const float* wq = (const float*)d_in[2];
  const float* wk = (const float*)d_in[3];
  const float* wv = (const float*)d_in[4];
  const float* wpos = (const float*)d_in[5];
  const float* pds = (const float*)d_in[6];
  float* out = (float*)d_out;

  char* ws = (char*)d_ws;
  bf16_t* kvK = (bf16_t*)ws;                       // big: K rows / small: interleaved kv
  bf16_t* vtws = (bf16_t*)(ws + kVtOff);
  bf16_t* wt = (bf16_t*)(ws + kWtOff);
  float* sinb = (float*)(ws + kSinOff);
  bf16_t* sinbf = (bf16_t*)(ws + kSinBfOff);
  float* ssb = (float*)(ws + kSsOff);
  bf16_t* hsb = (bf16_t*)(ws + kHsbOff);
  bf16_t* qb = (bf16_t*)(ws + kQbOff);

  const bool big = ws_size >= kWsNeedBig;

  transpose_w<<<dim3(48, 48, 3), dim3(32, 8), 0, stream>>>(wq, wk, wv, wt);
  convert_hs<<<dim3(2048), 256, 0, stream>>>(hs, hsb);
  sinemb_kernel<<<dim3(6, 13), 256, 0, stream>>>(wpos, sinb, sinbf);
  compute_ss<<<1, 192, 0, stream>>>(pds, ssb);

  if (big) {
    gemm_qkv_t<1><<<dim3(kNQKV / 128, kM / 128), 256, 0, stream>>>(
        hsb, wt, nullptr, kvK, vtws, qb, ssb);
    attn_mfma<<<dim3(86, kB, kH), 256, 0, stream>>>(kvK, vtws, mask, sinbf, qb, out);
  } else {
    gemm_qkv_t<0><<<dim3(kNQKV / 128, kM / 128), 256, 0, stream>>>(
        hsb, wt, out, kvK, nullptr, nullptr, nullptr);
    attn_kernel<<<dim3(kU, kB, kH), 256, 0, stream>>>(kvK, mask, sinb, pds, out);
  }
}

// Round 4
// 551.653 us; speedup vs baseline: 2.2914x; 1.1088x over previous
//
#include <hip/hip_runtime.h>
#include <hip/hip_bf16.h>
#include <cstdint>
#include <cstddef>

typedef __bf16 bf16x8 __attribute__((ext_vector_type(8)));
typedef __bf16 bf16x4_t __attribute__((ext_vector_type(4)));
typedef float f32x4 __attribute__((ext_vector_type(4)));
using bf16_t = __hip_bfloat16;

constexpr int kHID = 1536;
constexpr int kH = 8;
constexpr int kD = 192;
constexpr int kW = 12;
constexpr int kC = 24;
constexpr int kF = 13;
constexpr int kB = 4;
constexpr int kT = 4096;
constexpr int kU = 342;        // ceil(T/W)
constexpr int kNQKV = 4608;    // 3*HID
constexpr int kM = kB * kT;    // 16384
constexpr int kKV = 2 * kHID;  // 3072 (old interleaved layout, small mode)

// ws layout (bytes): see round-2; unchanged.
constexpr size_t kVtOff = 50331648;
constexpr size_t kWtOff = 100663296;
constexpr size_t kSinOff = kWtOff + (size_t)kNQKV * kHID * 2;      // 114819072
constexpr size_t kSinBfOff = kSinOff + (size_t)kF * kHID * 4;
constexpr size_t kSsOff = kSinBfOff + (size_t)16 * kHID * 2;
constexpr size_t kHsbOff = kSsOff + 1024;
constexpr size_t kQbOff = kHsbOff + (size_t)kM * kHID * 2;
constexpr size_t kWsNeedSmall = kQbOff;                             // 165,280,768
constexpr size_t kWsNeedBig = kQbOff + (size_t)kM * kHID * 2;       // 215,612,416

// async global->LDS, 16 bytes per lane (global_load_lds_dwordx4)
__device__ __forceinline__ void load_lds16(const void* g, void* l) {
  __builtin_amdgcn_global_load_lds(
      (const __attribute__((address_space(1))) void*)g,
      (__attribute__((address_space(3))) void*)l, 16, 0, 0);
}

// ---------------------------------------------------------------------------
// Kernel 1: transpose + concat weights (fp32 in) -> wt[n][k] (bf16)
// ---------------------------------------------------------------------------
__global__ __launch_bounds__(256) void transpose_w(const float* __restrict__ wq,
                                                   const float* __restrict__ wk,
                                                   const float* __restrict__ wv,
                                                   bf16_t* __restrict__ wt) {
  __shared__ bf16_t tile[32][33];
  const int s = blockIdx.z;
  const float* w = (s == 0) ? wq : (s == 1) ? wk : wv;
  const int k0 = blockIdx.x * 32, n0 = blockIdx.y * 32;
  for (int i = threadIdx.y; i < 32; i += 8)
    tile[i][threadIdx.x] = (bf16_t)w[(size_t)(k0 + i) * kHID + n0 + threadIdx.x];
  __syncthreads();
  for (int i = threadIdx.y; i < 32; i += 8)
    wt[(size_t)(s * kHID + n0 + i) * kHID + k0 + threadIdx.x] = tile[threadIdx.x][i];
}

// ---------------------------------------------------------------------------
// Kernel 1b: hs fp32 -> bf16
// ---------------------------------------------------------------------------
__global__ __launch_bounds__(256) void convert_hs(const float* __restrict__ hs,
                                                  bf16_t* __restrict__ hsb) {
  const size_t total = (size_t)kM * kHID;
  const size_t stride = (size_t)gridDim.x * 256 * 8;
  for (size_t i = ((size_t)blockIdx.x * 256 + threadIdx.x) * 8; i < total; i += stride) {
    f32x4 a = *(const f32x4*)(hs + i);
    f32x4 b = *(const f32x4*)(hs + i + 4);
    bf16x8 o;
#pragma unroll
    for (int e = 0; e < 4; e++) { o[e] = (__bf16)a[e]; o[e + 4] = (__bf16)b[e]; }
    *(bf16x8*)(hsb + i) = o;
  }
}

// ---------------------------------------------------------------------------
// Kernel 2 (OLD, small-mode fallback): sin_emb = ts(pos) @ w_pos
// ---------------------------------------------------------------------------
__global__ __launch_bounds__(256) void sinemb_kernel(const float* __restrict__ w_pos,
                                                     float* __restrict__ sinb,
                                                     bf16_t* __restrict__ sinbf) {
  __shared__ float ts[kHID];
  const int f = blockIdx.y;
  const int n = blockIdx.x * 256 + threadIdx.x;
  const float pos = (float)(12 - f);
  const float log_inc = logf(10000.0f) / 767.0f;
  for (int j = threadIdx.x; j < 768; j += 256) {
    float inv = expf(-(float)j * log_inc);
    float a = pos * inv;
    ts[j] = sinf(a);
    ts[768 + j] = cosf(a);
  }
  __syncthreads();
  float acc = 0.0f;
  for (int m = 0; m < kHID; m++) acc += ts[m] * w_pos[(size_t)m * kHID + n];
  sinb[f * kHID + n] = acc;
  sinbf[f * kHID + n] = (bf16_t)acc;
  if (f == 0) {
    sinbf[13 * kHID + n] = (bf16_t)0.0f;
    sinbf[14 * kHID + n] = (bf16_t)0.0f;
    sinbf[15 * kHID + n] = (bf16_t)0.0f;
  }
}

// ---------------------------------------------------------------------------
// Kernel 2-fast stage 1: partial dot over m-segment of 128, all 13 f.
// grid (6 n-chunks, 12 m-segs), block 256. sinp[ms][f][n] (uses d_out scratch).
// ---------------------------------------------------------------------------
__global__ __launch_bounds__(256) void sinemb_part(const float* __restrict__ w_pos,
                                                   float* __restrict__ sinp) {
  __shared__ float tsL[kF][128];
  const int nc = blockIdx.x;   // 0..5
  const int ms = blockIdx.y;   // 0..11
  const int tid = threadIdx.x;
  const float log_inc = logf(10000.0f) / 767.0f;
  for (int i = tid; i < kF * 128; i += 256) {
    int f = i >> 7, ml = i & 127;
    int m = ms * 128 + ml;
    float pos = (float)(12 - f);
    float v;
    if (m < 768) v = sinf(pos * expf(-(float)m * log_inc));
    else v = cosf(pos * expf(-(float)(m - 768) * log_inc));
    tsL[f][ml] = v;
  }
  __syncthreads();
  const int n = nc * 256 + tid;
  float acc[kF] = {};
  for (int ml = 0; ml < 128; ml++) {
    float wp = w_pos[(size_t)(ms * 128 + ml) * kHID + n];
#pragma unroll
    for (int f = 0; f < kF; f++) acc[f] += tsL[f][ml] * wp;
  }
#pragma unroll
  for (int f = 0; f < kF; f++) sinp[((size_t)ms * kF + f) * kHID + n] = acc[f];
}

// ---------------------------------------------------------------------------
// Kernel 2-fast stage 2: reduce 12 partials -> sinb (f32) + sinbf (bf16).
// ---------------------------------------------------------------------------
__global__ __launch_bounds__(256) void sinemb_reduce(const float* __restrict__ sinp,
                                                     float* __restrict__ sinb,
                                                     bf16_t* __restrict__ sinbf) {
  int i = blockIdx.x * 256 + threadIdx.x;
  if (i >= kF * kHID) return;
  int f = i / kHID, n = i % kHID;
  float s = 0.0f;
#pragma unroll
  for (int ms = 0; ms < 12; ms++) s += sinp[((size_t)ms * kF + f) * kHID + n];
  sinb[i] = s;
  sinbf[i] = (bf16_t)s;
  if (f == 0) {
    sinbf[13 * kHID + n] = (bf16_t)0.0f;
    sinbf[14 * kHID + n] = (bf16_t)0.0f;
    sinbf[15 * kHID + n] = (bf16_t)0.0f;
  }
}

// ---------------------------------------------------------------------------
// Kernel 2b: ss[d] = D^-0.5/ln2 * softplus(pds[d])
// ---------------------------------------------------------------------------
__global__ void compute_ss(const float* __restrict__ pds, float* __restrict__ ssb) {
  int d = threadIdx.x;
  if (d < kD) {
    float p = pds[d];
    float sp = log1pf(expf(p));
    ssb[d] = (1.0f / (sqrtf(192.0f) * logf(2.0f))) * sp;
  }
}

// ---------------------------------------------------------------------------
// Kernel 3 (fallback): 128x128 m97-structure QKV GEMM (round-2, proven).
// ---------------------------------------------------------------------------
template <int MODE>
__global__ __launch_bounds__(256) void gemm_qkv_t(const bf16_t* __restrict__ hsb,
                                                  const bf16_t* __restrict__ wt,
                                                  float* __restrict__ qout,
                                                  bf16_t* __restrict__ kvout,
                                                  bf16_t* __restrict__ vtws,
                                                  bf16_t* __restrict__ qbout,
                                                  const float* __restrict__ ssb) {
  __shared__ bf16_t As[128 * 32];
  __shared__ bf16_t Bs[128 * 32];
  const int tid = threadIdx.x;
  const int lane = tid & 63, wid = tid >> 6;
  const int t0 = blockIdx.y * 128, n0 = blockIdx.x * 128;
  const int mb = lane & 15, quad = lane >> 4;
  const int wrow = (wid >> 1) * 64, wcol = (wid & 1) * 64;

  f32x4 acc[4][4] = {};

  const int c0 = tid, c1 = tid + 256;
  const bf16_t* a0 = hsb + (size_t)(t0 + (c0 >> 2)) * kHID + (c0 & 3) * 8;
  const bf16_t* a1 = hsb + (size_t)(t0 + (c1 >> 2)) * kHID + (c1 & 3) * 8;
  const bf16_t* b0 = wt + (size_t)(n0 + (c0 >> 2)) * kHID + (c0 & 3) * 8;
  const bf16_t* b1 = wt + (size_t)(n0 + (c1 >> 2)) * kHID + (c1 & 3) * 8;
  bf16_t* lA0 = &As[c0 * 8];
  bf16_t* lA1 = &As[c1 * 8];
  bf16_t* lB0 = &Bs[c0 * 8];
  bf16_t* lB1 = &Bs[c1 * 8];

  for (int k0 = 0; k0 < kHID; k0 += 32) {
    __syncthreads();
    load_lds16(a0, lA0);
    load_lds16(a1, lA1);
    load_lds16(b0, lB0);
    load_lds16(b1, lB1);
    a0 += 32; a1 += 32; b0 += 32; b1 += 32;
    __syncthreads();

    bf16x8 af[4], bg[4];
#pragma unroll
    for (int i = 0; i < 4; i++)
      af[i] = *(const bf16x8*)(&As[(wrow + i * 16 + mb) * 32 + quad * 8]);
#pragma unroll
    for (int j = 0; j < 4; j++)
      bg[j] = *(const bf16x8*)(&Bs[(wcol + j * 16 + mb) * 32 + quad * 8]);
#pragma unroll
    for (int i = 0; i < 4; i++)
#pragma unroll
      for (int j = 0; j < 4; j++)
        acc[i][j] = __builtin_amdgcn_mfma_f32_16x16x32_bf16(af[i], bg[j], acc[i][j], 0, 0, 0);
  }

  if constexpr (MODE == 0) {
    const bool isq = (n0 < kHID);
#pragma unroll
    for (int i = 0; i < 4; i++)
#pragma unroll
      for (int j = 0; j < 4; j++)
#pragma unroll
        for (int r = 0; r < 4; r++) {
          int row = t0 + wrow + i * 16 + quad * 4 + r;
          int col = wcol + j * 16 + mb;
          if (isq) {
            qout[(size_t)row * kHID + n0 + col] = acc[i][j][r];
          } else {
            kvout[(size_t)row * kKV + (n0 - kHID) + col] = (bf16_t)acc[i][j][r];
          }
        }
  } else {
    if (n0 < kHID) {
#pragma unroll
      for (int j = 0; j < 4; j++) {
        int colj = n0 + wcol + j * 16 + mb;
        float ssv = ssb[colj % kD];
#pragma unroll
        for (int i = 0; i < 4; i++)
#pragma unroll
          for (int r = 0; r < 4; r++) {
            int row = t0 + wrow + i * 16 + quad * 4 + r;
            qbout[(size_t)row * kHID + colj] = (bf16_t)(acc[i][j][r] * ssv);
          }
      }
    } else if (n0 < 2 * kHID) {
#pragma unroll
      for (int i = 0; i < 4; i++)
#pragma unroll
        for (int j = 0; j < 4; j++)
#pragma unroll
          for (int r = 0; r < 4; r++) {
            int row = t0 + wrow + i * 16 + quad * 4 + r;
            int col = (n0 - kHID) + wcol + j * 16 + mb;
            kvout[(size_t)row * kHID + col] = (bf16_t)acc[i][j][r];
          }
    } else {
#pragma unroll
      for (int i = 0; i < 4; i++)
#pragma unroll
        for (int j = 0; j < 4; j++) {
          int vcol = (n0 - 2 * kHID) + wcol + j * 16 + mb;
          int row = t0 + wrow + i * 16 + quad * 4;
          bf16x4_t vv;
#pragma unroll
          for (int r = 0; r < 4; r++) vv[r] = (__bf16)acc[i][j][r];
          *(bf16x4_t*)(vtws + (size_t)vcol * kM + row) = vv;
        }
    }
  }
}

// ---------------------------------------------------------------------------
// Kernel 3-new: 256x256 8-phase QKV GEMM (T2 swizzle + T3/T4 counted vmcnt +
// T5 setprio). 512 threads = 8 waves (2 wm x 4 wn), per-wave C = 128x64.
// Dynamic LDS 128 KiB. Audited: uniform control flow (no divergent barrier);
// vmcnt(6) at phases 0/2 completes exactly the half-tiles consumed next;
// all stages into nxt issued after the end-of-tile barrier closing its reads.
// Swizzle: LDS 16B-chunk c of row r holds global chunk c ^ ((r>>2)&3)
// (linear glds dest + inverse-swizzled source + swizzled ds_read, rule #21).
// ---------------------------------------------------------------------------
__global__ __launch_bounds__(512, 2) void gemm256(const bf16_t* __restrict__ hsb,
                                                  const bf16_t* __restrict__ wt,
                                                  bf16_t* __restrict__ kvout,
                                                  bf16_t* __restrict__ vtws,
                                                  bf16_t* __restrict__ qbout,
                                                  const float* __restrict__ ssb) {
  extern __shared__ __align__(16) char sm[];
  const int tid = threadIdx.x;
  const int lane = tid & 63;
  const int wid = tid >> 6;
  const int mb = lane & 15, quad = lane >> 4;
  const int wm = wid >> 2, wn = wid & 3;
  const int t0 = blockIdx.y * 256, n0 = blockIdx.x * 256;

  // staging: per half-tile 1024 16B-chunks; thread covers i0 = tid, i1 = tid+512
  const int i0 = tid, i1 = tid + 512;
  const int r0 = i0 >> 2, cs0 = (i0 & 3) ^ ((r0 >> 2) & 3);
  const int r1 = i1 >> 2, cs1 = (i1 & 3) ^ ((r1 >> 2) & 3);
  const bf16_t* aS0 = hsb + (size_t)(t0 + r0) * kHID + cs0 * 8;
  const bf16_t* aS1 = hsb + (size_t)(t0 + r1) * kHID + cs1 * 8;
  const bf16_t* bS0 = wt + (size_t)(n0 + r0) * kHID + cs0 * 8;
  const bf16_t* bS1 = wt + (size_t)(n0 + r1) * kHID + cs1 * 8;

#define AH(buf, kh) (sm + (buf) * 32768 + (kh) * 16384)
#define BH(buf, kh) (sm + 65536 + (buf) * 32768 + (kh) * 16384)
#define STAGE_A(buf, kh, kt) do { int ko_ = (kt) * 64 + (kh) * 32; \
    load_lds16(aS0 + ko_, AH(buf, kh) + i0 * 16); \
    load_lds16(aS1 + ko_, AH(buf, kh) + i1 * 16); } while (0)
#define STAGE_B(buf, kh, kt) do { int ko_ = (kt) * 64 + (kh) * 32; \
    load_lds16(bS0 + ko_, BH(buf, kh) + i0 * 16); \
    load_lds16(bS1 + ko_, BH(buf, kh) + i1 * 16); } while (0)

  // ds_read: byte = row*64 + swizzled 16B chunk; swz chunk = quad ^ ((mb>>2)&3)
  const int sw16 = (quad ^ ((mb >> 2) & 3)) * 16;
  const int aRow = wm * 128 + mb;  // + mf*16 (+64 for mh=1)
  const int bRow = wn * 64 + mb;   // + nf*16

  f32x4 acc[8][4] = {};
  bf16x8 af[4], bfr[4];

  // prologue: full tile 0 into buf 0 (issue order A0,B0,A1,B1)
  STAGE_A(0, 0, 0); STAGE_B(0, 0, 0); STAGE_A(0, 1, 0); STAGE_B(0, 1, 0);

  for (int kt = 0; kt < 24; kt++) {
    const int cur = kt & 1, nxt = cur ^ 1;
    const int ktn = (kt < 23) ? kt + 1 : 23;  // last iter: harmless restage
    const char* Ac0 = AH(cur, 0); const char* Bc0 = BH(cur, 0);
    const char* Ac1 = AH(cur, 1); const char* Bc1 = BH(cur, 1);

    // ---- phase 0: kh=0, mh=0 ----
    STAGE_A(nxt, 0, ktn);
    asm volatile("s_waitcnt vmcnt(6)" ::: "memory");
    __builtin_amdgcn_s_barrier();
    __builtin_amdgcn_sched_barrier(0);
#pragma unroll
    for (int x = 0; x < 4; x++)
      af[x] = *(const bf16x8*)(Ac0 + (size_t)(aRow + x * 16) * 64 + sw16);
#pragma unroll
    for (int x = 0; x < 4; x++)
      bfr[x] = *(const bf16x8*)(Bc0 + (size_t)(bRow + x * 16) * 64 + sw16);
    __builtin_amdgcn_s_setprio(1);
#pragma unroll
    for (int i = 0; i < 4; i++)
#pragma unroll
      for (int j = 0; j < 4; j++)
        acc[i][j] = __builtin_amdgcn_mfma_f32_16x16x32_bf16(af[i], bfr[j], acc[i][j], 0, 0, 0);
    __builtin_amdgcn_s_setprio(0);

    // ---- phase 1: kh=0, mh=1 (reuse bfr) ----
    STAGE_B(nxt, 0, ktn);
#pragma unroll
    for (int x = 0; x < 4; x++)
      af[x] = *(const bf16x8*)(Ac0 + (size_t)(aRow + 64 + x * 16) * 64 + sw16);
    __builtin_amdgcn_s_setprio(1);
#pragma unroll
    for (int i = 0; i < 4; i++)
#pragma unroll
      for (int j = 0; j < 4; j++)
        acc[4 + i][j] = __builtin_amdgcn_mfma_f32_16x16x32_bf16(af[i], bfr[j], acc[4 + i][j], 0, 0, 0);
    __builtin_amdgcn_s_setprio(0);

    // ---- phase 2: kh=1, mh=0 ----
    STAGE_A(nxt, 1, ktn);
    asm volatile("s_waitcnt vmcnt(6)" ::: "memory");
    __builtin_amdgcn_s_barrier();
    __builtin_amdgcn_sched_barrier(0);
#pragma unroll
    for (int x = 0; x < 4; x++)
      af[x] = *(const bf16x8*)(Ac1 + (size_t)(aRow + x * 16) * 64 + sw16);
#pragma unroll
    for (int x = 0; x < 4; x++)
      bfr[x] = *(const bf16x8*)(Bc1 + (size_t)(bRow + x * 16) * 64 + sw16);
    __builtin_amdgcn_s_setprio(1);
#pragma unroll
    for (int i = 0; i < 4; i++)
#pragma unroll
      for (int j = 0; j < 4; j++)
        acc[i][j] = __builtin_amdgcn_mfma_f32_16x16x32_bf16(af[i], bfr[j], acc[i][j], 0, 0, 0);
    __builtin_amdgcn_s_setprio(0);

    // ---- phase 3: kh=1, mh=1 (reuse bfr) ----
    STAGE_B(nxt, 1, ktn);
#pragma unroll
    for (int x = 0; x < 4; x++)
      af[x] = *(const bf16x8*)(Ac1 + (size_t)(aRow + 64 + x * 16) * 64 + sw16);
    __builtin_amdgcn_s_setprio(1);
#pragma unroll
    for (int i = 0; i < 4; i++)
#pragma unroll
      for (int j = 0; j < 4; j++)
        acc[4 + i][j] = __builtin_amdgcn_mfma_f32_16x16x32_bf16(af[i], bfr[j], acc[4 + i][j], 0, 0, 0);
    __builtin_amdgcn_s_setprio(0);

    __builtin_amdgcn_s_barrier();  // all reads of cur done before anyone stages over it
    __builtin_amdgcn_sched_barrier(0);
  }
#undef AH
#undef BH
#undef STAGE_A
#undef STAGE_B

  // epilogue: D row = t0 + wm*128 + i*16 + quad*4 + r ; col = n0 + wn*64 + j*16 + mb
  if (n0 < kHID) {  // Q: scale by ss[col%192], bf16
#pragma unroll
    for (int j = 0; j < 4; j++) {
      int colj = n0 + wn * 64 + j * 16 + mb;
      float ssv = ssb[colj % kD];
#pragma unroll
      for (int i = 0; i < 8; i++)
#pragma unroll
        for (int r = 0; r < 4; r++) {
          int row = t0 + wm * 128 + i * 16 + quad * 4 + r;
          qbout[(size_t)row * kHID + colj] = (bf16_t)(acc[i][j][r] * ssv);
        }
    }
  } else if (n0 < 2 * kHID) {  // K rows
#pragma unroll
    for (int i = 0; i < 8; i++)
#pragma unroll
      for (int j = 0; j < 4; j++)
#pragma unroll
        for (int r = 0; r < 4; r++) {
          int row = t0 + wm * 128 + i * 16 + quad * 4 + r;
          int col = (n0 - kHID) + wn * 64 + j * 16 + mb;
          kvout[(size_t)row * kHID + col] = (bf16_t)acc[i][j][r];
        }
  } else {  // V transposed: vtws[vcol][row], 4 rows per 8B store
#pragma unroll
    for (int i = 0; i < 8; i++)
#pragma unroll
      for (int j = 0; j < 4; j++) {
        int vcol = (n0 - 2 * kHID) + wn * 64 + j * 16 + mb;
        int row = t0 + wm * 128 + i * 16 + quad * 4;
        bf16x4_t vv;
#pragma unroll
        for (int r = 0; r < 4; r++) vv[r] = (__bf16)acc[i][j][r];
        *(bf16x4_t*)(vtws + (size_t)vcol * kM + row) = vv;
      }
  }
}

// ---------------------------------------------------------------------------
// Kernel 4 (big-ws): MFMA local relative attention (unchanged from round 2).
// ---------------------------------------------------------------------------
__global__ __launch_bounds__(256) void attn_mfma(const bf16_t* __restrict__ kvK,
                                                 const bf16_t* __restrict__ vtws,
                                                 const unsigned char* __restrict__ mask,
                                                 const bf16_t* __restrict__ sinbf,
                                                 const bf16_t* __restrict__ qb,
                                                 float* __restrict__ out) {
  const int g = blockIdx.x, b = blockIdx.y, h = blockIdx.z;
  const int tid = threadIdx.x;
  const int lane = tid & 63, wv = tid >> 6;
  const int w = lane & 15, quad = lane >> 4;
  const int tb = g * 48 - 12;
  const int u = g * 4 + wv;

  __shared__ bf16_t Ks[68 * 192];
  __shared__ bf16_t Vt[192 * 80];
  __shared__ __align__(16) char scr[4][1280];
  __shared__ int vld[68];

  float* bdl = (float*)scr[wv];
  bf16_t* Pl = (bf16_t*)scr[wv];

  int tq = u * kW + w;
  int qrow = (u < kU && tq < kT) ? (b * kT + tq) : (b * kT);
  const bf16_t* qptr = qb + (size_t)qrow * kHID + h * kD + quad * 8;
  const bf16_t* sptr = sinbf + (size_t)w * kHID + h * kD + quad * 8;
  bf16x8 qf[6], sf[6];
#pragma unroll
  for (int ks = 0; ks < 6; ks++) {
    qf[ks] = *(const bf16x8*)(qptr + ks * 32);
    sf[ks] = *(const bf16x8*)(sptr + ks * 32);
  }

  if (tid < 68) {
    int p = tb + tid;
    vld[tid] = (p >= 0 && p < kT && mask[b * kT + p] == 0) ? 1 : 0;
  }

  const char* kvb = (const char*)kvK;
#pragma unroll
  for (int it = 0; it < 7; it++) {
    int i = it * 256 + tid;
    if (i >= 1632) i -= 1632;
    int r = i / 24, cb = (i % 24) * 16;
    int row = b * kT + tb + r;
    row = row < 0 ? 0 : (row > kM - 1 ? kM - 1 : row);
    const char* src = kvb + (size_t)row * 3072 + h * 384 + (cb ^ ((r & 7) << 4));
    load_lds16(src, (char*)Ks + i * 16);
  }
  const char* vtb = (const char*)vtws;
#pragma unroll
  for (int it = 0; it < 8; it++) {
    int i = it * 256 + tid;
    if (i >= 1920) i -= 1920;
    int d = i / 10, j = i % 10;
    int e = b * kT + tb - 4 + j * 8;
    e = e < 0 ? 0 : (e > kM - 8 ? kM - 8 : e);
    const char* src = vtb + ((size_t)(h * kD + d) * kM + e) * 2;
    load_lds16(src, (char*)Vt + i * 16);
  }
  __syncthreads();

  f32x4 ac0 = {0.f, 0.f, 0.f, 0.f}, ac1 = {0.f, 0.f, 0.f, 0.f}, bdv = {0.f, 0.f, 0.f, 0.f};
  const int r0 = wv * kW + w;
  const int r1 = r0 + 16;
#pragma unroll
  for (int ks = 0; ks < 6; ks++) {
    int kb = ks * 64 + quad * 16;
    bf16x8 ka0 = *(const bf16x8*)((const char*)Ks + (size_t)r0 * 384 + (kb ^ ((r0 & 7) << 4)));
    bf16x8 ka1 = *(const bf16x8*)((const char*)Ks + (size_t)r1 * 384 + (kb ^ ((r1 & 7) << 4)));
    ac0 = __builtin_amdgcn_mfma_f32_16x16x32_bf16(ka0, qf[ks], ac0, 0, 0, 0);
    ac1 = __builtin_amdgcn_mfma_f32_16x16x32_bf16(ka1, qf[ks], ac1, 0, 0, 0);
    bdv = __builtin_amdgcn_mfma_f32_16x16x32_bf16(sf[ks], qf[ks], bdv, 0, 0, 0);
  }

  *(f32x4*)&bdl[w * 16 + quad * 4] = bdv;
  asm volatile("s_waitcnt lgkmcnt(0)" ::: "memory");

  float l[8];
#pragma unroll
  for (int T = 0; T < 2; T++)
#pragma unroll
    for (int r = 0; r < 4; r++) {
      int c = T * 16 + quad * 4 + r;
      int f = c - w;
      int fr = f < 0 ? 0 : (f > 15 ? 15 : f);
      float a = T ? ac1[r] : ac0[r];
      float bb = bdl[w * 16 + fr];
      bool val = (f >= 0) && (f <= 12) && (c < kC) && (vld[wv * kW + c] != 0);
      float x2 = (a + bb) * 0.04f;
      float ee = __expf(x2);
      float th = (ee - 1.0f) * __builtin_amdgcn_rcpf(ee + 1.0f);
      l[T * 4 + r] = val ? 50.0f * th : -3.4028234663852886e38f;
    }

  float m = l[0];
#pragma unroll
  for (int k = 1; k < 8; k++) m = fmaxf(m, l[k]);
  m = fmaxf(m, __shfl_xor(m, 16, 64));
  m = fmaxf(m, __shfl_xor(m, 32, 64));
  float e8[8], s = 0.0f;
#pragma unroll
  for (int k = 0; k < 8; k++) { e8[k] = __expf(l[k] - m); s += e8[k]; }
  s += __shfl_xor(s, 16, 64);
  s += __shfl_xor(s, 32, 64);
  float inv = 1.0f / s;

#pragma unroll
  for (int T = 0; T < 2; T++) {
    bf16x4_t pk;
#pragma unroll
    for (int r = 0; r < 4; r++) {
      int c = T * 16 + quad * 4 + r;
      float p = (c < kC) ? e8[T * 4 + r] * inv : 0.0f;
      pk[r] = (__bf16)p;
    }
    *(bf16x4_t*)&Pl[w * 40 + T * 16 + quad * 4] = pk;
  }
  asm volatile("s_waitcnt lgkmcnt(0)" ::: "memory");
  __builtin_amdgcn_sched_barrier(0);

  bf16x8 pa = *(const bf16x8*)&Pl[w * 40 + quad * 8];
  const int cl0 = 4 + wv * kW + quad * 8;
  const bool uok = (u < kU);
#pragma unroll
  for (int T = 0; T < 12; T++) {
    bf16x4_t v0 = *(const bf16x4_t*)&Vt[(T * 16 + w) * 80 + cl0];
    bf16x4_t v1 = *(const bf16x4_t*)&Vt[(T * 16 + w) * 80 + cl0 + 4];
    bf16x8 vf;
#pragma unroll
    for (int e2 = 0; e2 < 4; e2++) { vf[e2] = v0[e2]; vf[e2 + 4] = v1[e2]; }
    f32x4 oz = {0.f, 0.f, 0.f, 0.f};
    oz = __builtin_amdgcn_mfma_f32_16x16x32_bf16(pa, vf, oz, 0, 0, 0);
    if (uok) {
#pragma unroll
      for (int r = 0; r < 4; r++) {
        int wr = quad * 4 + r;
        int t = u * kW + wr;
        if (wr < kW && t < kT)
          out[((size_t)(b * kT + t)) * kHID + h * kD + T * 16 + w] = oz[r];
      }
    }
  }
}

// ---------------------------------------------------------------------------
// Kernel 4 (fallback, small ws): round-1 scalar attention (unchanged).
// ---------------------------------------------------------------------------
__global__ __launch_bounds__(256) void attn_kernel(const bf16_t* __restrict__ kv,
                                                   const unsigned char* __restrict__ mask,
                                                   const float* __restrict__ sinb,
                                                   const float* __restrict__ pds,
                                                   float* __restrict__ out) {
  const int u = blockIdx.x, b = blockIdx.y, h = blockIdx.z;
  const int tid = threadIdx.x;

  __shared__ float qs[kW][kD + 1];
  __shared__ float ks[kC][kD + 1];
  __shared__ float vs[kC][kD + 1];
  __shared__ float sins[kF][kD + 1];
  __shared__ float lg[kW][kC + 1];
  __shared__ float ss[kD];
  __shared__ int validc[kC];

  if (tid < kD) {
    float p = pds[tid];
    float sp = log1pf(expf(p));
    ss[tid] = (1.0f / (sqrtf(192.0f) * logf(2.0f))) * sp;
  }
  if (tid < kC) {
    int p = u * kW + tid - 12;
    validc[tid] = (p >= 0 && p < kT && mask[b * kT + p] == 0) ? 1 : 0;
  }
  __syncthreads();

  for (int i = tid; i < kW * kD; i += 256) {
    int w = i / kD, d = i % kD;
    int t = u * kW + w;
    float v = 0.0f;
    if (t < kT) v = out[((size_t)(b * kT + t)) * kHID + h * kD + d] * ss[d];
    qs[w][d] = v;
  }
  for (int i = tid; i < kC * kD; i += 256) {
    int c = i / kD, d = i % kD;
    int p = u * kW + c - 12;
    float kval = 0.0f, vval = 0.0f;
    if (p >= 0 && p < kT) {
      size_t base = (size_t)(b * kT + p) * kKV;
      kval = (float)kv[base + h * kD + d];
      vval = (float)kv[base + kHID + h * kD + d];
    }
    ks[c][d] = kval;
    vs[c][d] = vval;
  }
  for (int i = tid; i < kF * kD; i += 256) {
    int f = i / kD, d = i % kD;
    sins[f][d] = sinb[f * kHID + h * kD + d];
  }
  __syncthreads();

  for (int i = tid; i < kW * kC; i += 256) {
    int w = i / kC, c = i % kC;
    float l = -3.4028234663852886e38f;
    int f = c - w;
    if (f >= 0 && f <= 12 && validc[c]) {
      float ac = 0.0f, bd = 0.0f;
      for (int d = 0; d < kD; d++) {
        float q = qs[w][d];
        ac += q * ks[c][d];
        bd += q * sins[f][d];
      }
      l = tanhf((ac + bd) * (1.0f / 50.0f)) * 50.0f;
    }
    lg[w][c] = l;
  }
  __syncthreads();

  if (tid < kW) {
    float m = -3.4028234663852886e38f;
#pragma unroll
    for (int c = 0; c < kC; c++) m = fmaxf(m, lg[tid][c]);
    float e[kC];
    float s = 0.0f;
#pragma unroll
    for (int c = 0; c < kC; c++) {
      float ex = expf(lg[tid][c] - m);
      e[c] = ex;
      s += ex;
    }
    float inv = 1.0f / s;
#pragma unroll
    for (int c = 0; c < kC; c++) lg[tid][c] = e[c] * inv;
  }
  __syncthreads();

  for (int i = tid; i < kW * kD; i += 256) {
    int w = i / kD, d = i % kD;
    int t = u * kW + w;
    if (t >= kT) continue;
    float acc = 0.0f;
#pragma unroll
    for (int c = 0; c < 13; c++) acc += lg[w][w + c] * vs[w + c][d];
    out[((size_t)(b * kT + t)) * kHID + h * kD + d] = acc;
  }
}

// ---------------------------------------------------------------------------
extern "C" void kernel_launch(void* const* d_in, const int* in_sizes, int n_in,
                              void* d_out, int out_size, void* d_ws, size_t ws_size,
                              hipStream_t stream) {
  if (ws_size < kWsNeedSmall) return;  // beacon: absmax == 3.92 means ws too small

  const float* hs = (const float*)d_in[0];
  const unsigned char* mask = (const unsigned char*)d_in[1];
  const float* wq = (const float*)d_in[2];
  const float* wk = (const float*)d_in[3];
  const float* wv = (const float*)d_in[4];
  const float* wpos = (const float*)d_in[5];
  const float* pds = (const float*)d_in[6];
  float* out = (float*)d_out;

  char* ws = (char*)d_ws;
  bf16_t* kvK = (bf16_t*)ws;
  bf16_t* vtws = (bf16_t*)(ws + kVtOff);
  bf16_t* wt = (bf16_t*)(ws + kWtOff);
  float* sinb = (float*)(ws + kSinOff);
  bf16_t* sinbf = (bf16_t*)(ws + kSinBfOff);
  float* ssb = (float*)(ws + kSsOff);
  bf16_t* hsb = (bf16_t*)(ws + kHsbOff);
  bf16_t* qb = (bf16_t*)(ws + kQbOff);

  const bool big = ws_size >= kWsNeedBig;

  // one-time opt-in for 128 KiB dynamic LDS; fall back to 128^2 GEMM if denied
  static int g_big_lds = -1;
  if (g_big_lds < 0) {
    g_big_lds = (hipFuncSetAttribute((const void*)gemm256,
                                     hipFuncAttributeMaxDynamicSharedMemorySize,
                                     131072) == hipSuccess) ? 1 : 0;
  }

  transpose_w<<<dim3(48, 48, 3), dim3(32, 8), 0, stream>>>(wq, wk, wv, wt);
  convert_hs<<<dim3(2048), 256, 0, stream>>>(hs, hsb);
  compute_ss<<<1, 192, 0, stream>>>(pds, ssb);

  if (big) {
    // fast sinemb: partials into d_out scratch (overwritten later by attn)
    float* sinp = (float*)d_out;
    sinemb_part<<<dim3(6, 12), 256, 0, stream>>>(wpos, sinp);
    sinemb_reduce<<<dim3(78), 256, 0, stream>>>(sinp, sinb, sinbf);
    bool ran256 = false;
    if (g_big_lds) {
      (void)hipGetLastError();  // clear stale error state
      gemm256<<<dim3(kNQKV / 256, kM / 256), 512, 131072, stream>>>(
          hsb, wt, kvK, vtws, qb, ssb);
      if (hipGetLastError() == hipSuccess) {
        ran256 = true;
      } else {
        g_big_lds = 0;  // don't retry the failing config
      }
    }
    if (!ran256) {
      gemm_qkv_t<1><<<dim3(kNQKV / 128, kM / 128), 256, 0, stream>>>(
          hsb, wt, nullptr, kvK, vtws, qb, ssb);
    }
    attn_mfma<<<dim3(86, kB, kH), 256, 0, stream>>>(kvK, vtws, mask, sinbf, qb, out);
  } else {
    sinemb_kernel<<<dim3(6, 13), 256, 0, stream>>>(wpos, sinb, sinbf);
    gemm_qkv_t<0><<<dim3(kNQKV / 128, kM / 128), 256, 0, stream>>>(
        hsb, wt, out, kvK, nullptr, nullptr, nullptr);
    attn_kernel<<<dim3(kU, kB, kH), 256, 0, stream>>>(kvK, mask, sinb, pds, out);
  }
}

// Round 7
// 547.465 us; speedup vs baseline: 2.3089x; 1.0077x over previous
//
#include <hip/hip_runtime.h>
#include <hip/hip_bf16.h>
#include <cstdint>
#include <cstddef>

typedef __bf16 bf16x8 __attribute__((ext_vector_type(8)));
typedef __bf16 bf16x4_t __attribute__((ext_vector_type(4)));
typedef float f32x4 __attribute__((ext_vector_type(4)));
using bf16_t = __hip_bfloat16;

constexpr int kHID = 1536;
constexpr int kH = 8;
constexpr int kD = 192;
constexpr int kW = 12;
constexpr int kC = 24;
constexpr int kF = 13;
constexpr int kB = 4;
constexpr int kT = 4096;
constexpr int kU = 342;        // ceil(T/W)
constexpr int kNQKV = 4608;    // 3*HID
constexpr int kM = kB * kT;    // 16384
constexpr int kKV = 2 * kHID;  // 3072 (old interleaved layout, small mode)

// ws layout (bytes): unchanged from round-2.
constexpr size_t kVtOff = 50331648;
constexpr size_t kWtOff = 100663296;
constexpr size_t kSinOff = kWtOff + (size_t)kNQKV * kHID * 2;      // 114819072
constexpr size_t kSinBfOff = kSinOff + (size_t)kF * kHID * 4;
constexpr size_t kSsOff = kSinBfOff + (size_t)16 * kHID * 2;
constexpr size_t kHsbOff = kSsOff + 1024;
constexpr size_t kQbOff = kHsbOff + (size_t)kM * kHID * 2;
constexpr size_t kWsNeedSmall = kQbOff;                             // 165,280,768
constexpr size_t kWsNeedBig = kQbOff + (size_t)kM * kHID * 2;       // 215,612,416

// async global->LDS, 16 bytes per lane (global_load_lds_dwordx4)
__device__ __forceinline__ void load_lds16(const void* g, void* l) {
  __builtin_amdgcn_global_load_lds(
      (const __attribute__((address_space(1))) void*)g,
      (__attribute__((address_space(3))) void*)l, 16, 0, 0);
}

// ---------------------------------------------------------------------------
// Kernel 1: transpose + concat weights (fp32 in) -> wt[n][k] (bf16)
// ---------------------------------------------------------------------------
__global__ __launch_bounds__(256) void transpose_w(const float* __restrict__ wq,
                                                   const float* __restrict__ wk,
                                                   const float* __restrict__ wv,
                                                   bf16_t* __restrict__ wt) {
  __shared__ bf16_t tile[32][33];
  const int s = blockIdx.z;
  const float* w = (s == 0) ? wq : (s == 1) ? wk : wv;
  const int k0 = blockIdx.x * 32, n0 = blockIdx.y * 32;
  for (int i = threadIdx.y; i < 32; i += 8)
    tile[i][threadIdx.x] = (bf16_t)w[(size_t)(k0 + i) * kHID + n0 + threadIdx.x];
  __syncthreads();
  for (int i = threadIdx.y; i < 32; i += 8)
    wt[(size_t)(s * kHID + n0 + i) * kHID + k0 + threadIdx.x] = tile[threadIdx.x][i];
}

// ---------------------------------------------------------------------------
// Kernel 1b: hs fp32 -> bf16
// ---------------------------------------------------------------------------
__global__ __launch_bounds__(256) void convert_hs(const float* __restrict__ hs,
                                                  bf16_t* __restrict__ hsb) {
  const size_t total = (size_t)kM * kHID;
  const size_t stride = (size_t)gridDim.x * 256 * 8;
  for (size_t i = ((size_t)blockIdx.x * 256 + threadIdx.x) * 8; i < total; i += stride) {
    f32x4 a = *(const f32x4*)(hs + i);
    f32x4 b = *(const f32x4*)(hs + i + 4);
    bf16x8 o;
#pragma unroll
    for (int e = 0; e < 4; e++) { o[e] = (__bf16)a[e]; o[e + 4] = (__bf16)b[e]; }
    *(bf16x8*)(hsb + i) = o;
  }
}

// ---------------------------------------------------------------------------
// Kernel 2 (small-mode fallback): sin_emb = ts(pos) @ w_pos
// ---------------------------------------------------------------------------
__global__ __launch_bounds__(256) void sinemb_kernel(const float* __restrict__ w_pos,
                                                     float* __restrict__ sinb,
                                                     bf16_t* __restrict__ sinbf) {
  __shared__ float ts[kHID];
  const int f = blockIdx.y;
  const int n = blockIdx.x * 256 + threadIdx.x;
  const float pos = (float)(12 - f);
  const float log_inc = logf(10000.0f) / 767.0f;
  for (int j = threadIdx.x; j < 768; j += 256) {
    float inv = expf(-(float)j * log_inc);
    float a = pos * inv;
    ts[j] = sinf(a);
    ts[768 + j] = cosf(a);
  }
  __syncthreads();
  float acc = 0.0f;
  for (int m = 0; m < kHID; m++) acc += ts[m] * w_pos[(size_t)m * kHID + n];
  sinb[f * kHID + n] = acc;
  sinbf[f * kHID + n] = (bf16_t)acc;
  if (f == 0) {
    sinbf[13 * kHID + n] = (bf16_t)0.0f;
    sinbf[14 * kHID + n] = (bf16_t)0.0f;
    sinbf[15 * kHID + n] = (bf16_t)0.0f;
  }
}

// ---------------------------------------------------------------------------
// Kernel 2-fast stage 1: partial dot over m-segment of 128, all 13 f.
// ---------------------------------------------------------------------------
__global__ __launch_bounds__(256) void sinemb_part(const float* __restrict__ w_pos,
                                                   float* __restrict__ sinp) {
  __shared__ float tsL[kF][128];
  const int nc = blockIdx.x;   // 0..5
  const int ms = blockIdx.y;   // 0..11
  const int tid = threadIdx.x;
  const float log_inc = logf(10000.0f) / 767.0f;
  for (int i = tid; i < kF * 128; i += 256) {
    int f = i >> 7, ml = i & 127;
    int m = ms * 128 + ml;
    float pos = (float)(12 - f);
    float v;
    if (m < 768) v = sinf(pos * expf(-(float)m * log_inc));
    else v = cosf(pos * expf(-(float)(m - 768) * log_inc));
    tsL[f][ml] = v;
  }
  __syncthreads();
  const int n = nc * 256 + tid;
  float acc[kF] = {};
  for (int ml = 0; ml < 128; ml++) {
    float wp = w_pos[(size_t)(ms * 128 + ml) * kHID + n];
#pragma unroll
    for (int f = 0; f < kF; f++) acc[f] += tsL[f][ml] * wp;
  }
#pragma unroll
  for (int f = 0; f < kF; f++) sinp[((size_t)ms * kF + f) * kHID + n] = acc[f];
}

// ---------------------------------------------------------------------------
// Kernel 2-fast stage 2: reduce 12 partials -> sinb (f32) + sinbf (bf16).
// ---------------------------------------------------------------------------
__global__ __launch_bounds__(256) void sinemb_reduce(const float* __restrict__ sinp,
                                                     float* __restrict__ sinb,
                                                     bf16_t* __restrict__ sinbf) {
  int i = blockIdx.x * 256 + threadIdx.x;
  if (i >= kF * kHID) return;
  int f = i / kHID, n = i % kHID;
  float s = 0.0f;
#pragma unroll
  for (int ms = 0; ms < 12; ms++) s += sinp[((size_t)ms * kF + f) * kHID + n];
  sinb[i] = s;
  sinbf[i] = (bf16_t)s;
  if (f == 0) {
    sinbf[13 * kHID + n] = (bf16_t)0.0f;
    sinbf[14 * kHID + n] = (bf16_t)0.0f;
    sinbf[15 * kHID + n] = (bf16_t)0.0f;
  }
}

// ---------------------------------------------------------------------------
// Kernel 2b: ss[d] = D^-0.5/ln2 * softplus(pds[d])
// ---------------------------------------------------------------------------
__global__ void compute_ss(const float* __restrict__ pds, float* __restrict__ ssb) {
  int d = threadIdx.x;
  if (d < kD) {
    float p = pds[d];
    float sp = log1pf(expf(p));
    ssb[d] = (1.0f / (sqrtf(192.0f) * logf(2.0f))) * sp;
  }
}

// ---------------------------------------------------------------------------
// Kernel 3 (fallback): 128x128 m97-structure QKV GEMM (round-2, proven).
// ---------------------------------------------------------------------------
template <int MODE>
__global__ __launch_bounds__(256) void gemm_qkv_t(const bf16_t* __restrict__ hsb,
                                                  const bf16_t* __restrict__ wt,
                                                  float* __restrict__ qout,
                                                  bf16_t* __restrict__ kvout,
                                                  bf16_t* __restrict__ vtws,
                                                  bf16_t* __restrict__ qbout,
                                                  const float* __restrict__ ssb) {
  __shared__ bf16_t As[128 * 32];
  __shared__ bf16_t Bs[128 * 32];
  const int tid = threadIdx.x;
  const int lane = tid & 63, wid = tid >> 6;
  const int t0 = blockIdx.y * 128, n0 = blockIdx.x * 128;
  const int mb = lane & 15, quad = lane >> 4;
  const int wrow = (wid >> 1) * 64, wcol = (wid & 1) * 64;

  f32x4 acc[4][4] = {};

  const int c0 = tid, c1 = tid + 256;
  const bf16_t* a0 = hsb + (size_t)(t0 + (c0 >> 2)) * kHID + (c0 & 3) * 8;
  const bf16_t* a1 = hsb + (size_t)(t0 + (c1 >> 2)) * kHID + (c1 & 3) * 8;
  const bf16_t* b0 = wt + (size_t)(n0 + (c0 >> 2)) * kHID + (c0 & 3) * 8;
  const bf16_t* b1 = wt + (size_t)(n0 + (c1 >> 2)) * kHID + (c1 & 3) * 8;
  bf16_t* lA0 = &As[c0 * 8];
  bf16_t* lA1 = &As[c1 * 8];
  bf16_t* lB0 = &Bs[c0 * 8];
  bf16_t* lB1 = &Bs[c1 * 8];

  for (int k0 = 0; k0 < kHID; k0 += 32) {
    __syncthreads();
    load_lds16(a0, lA0);
    load_lds16(a1, lA1);
    load_lds16(b0, lB0);
    load_lds16(b1, lB1);
    a0 += 32; a1 += 32; b0 += 32; b1 += 32;
    __syncthreads();

    bf16x8 af[4], bg[4];
#pragma unroll
    for (int i = 0; i < 4; i++)
      af[i] = *(const bf16x8*)(&As[(wrow + i * 16 + mb) * 32 + quad * 8]);
#pragma unroll
    for (int j = 0; j < 4; j++)
      bg[j] = *(const bf16x8*)(&Bs[(wcol + j * 16 + mb) * 32 + quad * 8]);
#pragma unroll
    for (int i = 0; i < 4; i++)
#pragma unroll
      for (int j = 0; j < 4; j++)
        acc[i][j] = __builtin_amdgcn_mfma_f32_16x16x32_bf16(af[i], bg[j], acc[i][j], 0, 0, 0);
  }

  if constexpr (MODE == 0) {
    const bool isq = (n0 < kHID);
#pragma unroll
    for (int i = 0; i < 4; i++)
#pragma unroll
      for (int j = 0; j < 4; j++)
#pragma unroll
        for (int r = 0; r < 4; r++) {
          int row = t0 + wrow + i * 16 + quad * 4 + r;
          int col = wcol + j * 16 + mb;
          if (isq) {
            qout[(size_t)row * kHID + n0 + col] = acc[i][j][r];
          } else {
            kvout[(size_t)row * kKV + (n0 - kHID) + col] = (bf16_t)acc[i][j][r];
          }
        }
  } else {
    if (n0 < kHID) {
#pragma unroll
      for (int j = 0; j < 4; j++) {
        int colj = n0 + wcol + j * 16 + mb;
        float ssv = ssb[colj % kD];
#pragma unroll
        for (int i = 0; i < 4; i++)
#pragma unroll
          for (int r = 0; r < 4; r++) {
            int row = t0 + wrow + i * 16 + quad * 4 + r;
            qbout[(size_t)row * kHID + colj] = (bf16_t)(acc[i][j][r] * ssv);
          }
      }
    } else if (n0 < 2 * kHID) {
#pragma unroll
      for (int i = 0; i < 4; i++)
#pragma unroll
        for (int j = 0; j < 4; j++)
#pragma unroll
          for (int r = 0; r < 4; r++) {
            int row = t0 + wrow + i * 16 + quad * 4 + r;
            int col = (n0 - kHID) + wcol + j * 16 + mb;
            kvout[(size_t)row * kHID + col] = (bf16_t)acc[i][j][r];
          }
    } else {
#pragma unroll
      for (int i = 0; i < 4; i++)
#pragma unroll
        for (int j = 0; j < 4; j++) {
          int vcol = (n0 - 2 * kHID) + wcol + j * 16 + mb;
          int row = t0 + wrow + i * 16 + quad * 4;
          bf16x4_t vv;
#pragma unroll
          for (int r = 0; r < 4; r++) vv[r] = (__bf16)acc[i][j][r];
          *(bf16x4_t*)(vtws + (size_t)vcol * kM + row) = vv;
        }
    }
  }
}

// ---------------------------------------------------------------------------
// Kernel 3-new: 256x256 8-phase QKV GEMM — ROUND-4 PASSING VERSION, verbatim.
// (64B-row LDS halves, vmcnt(6) at phases 0/2, setprio around MFMA.)
// ---------------------------------------------------------------------------
__global__ __launch_bounds__(512, 2) void gemm256(const bf16_t* __restrict__ hsb,
                                                  const bf16_t* __restrict__ wt,
                                                  bf16_t* __restrict__ kvout,
                                                  bf16_t* __restrict__ vtws,
                                                  bf16_t* __restrict__ qbout,
                                                  const float* __restrict__ ssb) {
  extern __shared__ __align__(16) char sm[];
  const int tid = threadIdx.x;
  const int lane = tid & 63;
  const int wid = tid >> 6;
  const int mb = lane & 15, quad = lane >> 4;
  const int wm = wid >> 2, wn = wid & 3;
  const int t0 = blockIdx.y * 256, n0 = blockIdx.x * 256;

  // staging: per half-tile 1024 16B-chunks; thread covers i0 = tid, i1 = tid+512
  const int i0 = tid, i1 = tid + 512;
  const int r0 = i0 >> 2, cs0 = (i0 & 3) ^ ((r0 >> 2) & 3);
  const int r1 = i1 >> 2, cs1 = (i1 & 3) ^ ((r1 >> 2) & 3);
  const bf16_t* aS0 = hsb + (size_t)(t0 + r0) * kHID + cs0 * 8;
  const bf16_t* aS1 = hsb + (size_t)(t0 + r1) * kHID + cs1 * 8;
  const bf16_t* bS0 = wt + (size_t)(n0 + r0) * kHID + cs0 * 8;
  const bf16_t* bS1 = wt + (size_t)(n0 + r1) * kHID + cs1 * 8;

#define AH(buf, kh) (sm + (buf) * 32768 + (kh) * 16384)
#define BH(buf, kh) (sm + 65536 + (buf) * 32768 + (kh) * 16384)
#define STAGE_A(buf, kh, kt) do { int ko_ = (kt) * 64 + (kh) * 32; \
    load_lds16(aS0 + ko_, AH(buf, kh) + i0 * 16); \
    load_lds16(aS1 + ko_, AH(buf, kh) + i1 * 16); } while (0)
#define STAGE_B(buf, kh, kt) do { int ko_ = (kt) * 64 + (kh) * 32; \
    load_lds16(bS0 + ko_, BH(buf, kh) + i0 * 16); \
    load_lds16(bS1 + ko_, BH(buf, kh) + i1 * 16); } while (0)

  // ds_read: byte = row*64 + swizzled 16B chunk; swz chunk = quad ^ ((mb>>2)&3)
  const int sw16 = (quad ^ ((mb >> 2) & 3)) * 16;
  const int aRow = wm * 128 + mb;  // + mf*16 (+64 for mh=1)
  const int bRow = wn * 64 + mb;   // + nf*16

  f32x4 acc[8][4] = {};
  bf16x8 af[4], bfr[4];

  // prologue: full tile 0 into buf 0 (issue order A0,B0,A1,B1)
  STAGE_A(0, 0, 0); STAGE_B(0, 0, 0); STAGE_A(0, 1, 0); STAGE_B(0, 1, 0);

  for (int kt = 0; kt < 24; kt++) {
    const int cur = kt & 1, nxt = cur ^ 1;
    const int ktn = (kt < 23) ? kt + 1 : 23;  // last iter: harmless restage
    const char* Ac0 = AH(cur, 0); const char* Bc0 = BH(cur, 0);
    const char* Ac1 = AH(cur, 1); const char* Bc1 = BH(cur, 1);

    // ---- phase 0: kh=0, mh=0 ----
    STAGE_A(nxt, 0, ktn);
    asm volatile("s_waitcnt vmcnt(6)" ::: "memory");
    __builtin_amdgcn_s_barrier();
    __builtin_amdgcn_sched_barrier(0);
#pragma unroll
    for (int x = 0; x < 4; x++)
      af[x] = *(const bf16x8*)(Ac0 + (size_t)(aRow + x * 16) * 64 + sw16);
#pragma unroll
    for (int x = 0; x < 4; x++)
      bfr[x] = *(const bf16x8*)(Bc0 + (size_t)(bRow + x * 16) * 64 + sw16);
    __builtin_amdgcn_s_setprio(1);
#pragma unroll
    for (int i = 0; i < 4; i++)
#pragma unroll
      for (int j = 0; j < 4; j++)
        acc[i][j] = __builtin_amdgcn_mfma_f32_16x16x32_bf16(af[i], bfr[j], acc[i][j], 0, 0, 0);
    __builtin_amdgcn_s_setprio(0);

    // ---- phase 1: kh=0, mh=1 (reuse bfr) ----
    STAGE_B(nxt, 0, ktn);
#pragma unroll
    for (int x = 0; x < 4; x++)
      af[x] = *(const bf16x8*)(Ac0 + (size_t)(aRow + 64 + x * 16) * 64 + sw16);
    __builtin_amdgcn_s_setprio(1);
#pragma unroll
    for (int i = 0; i < 4; i++)
#pragma unroll
      for (int j = 0; j < 4; j++)
        acc[4 + i][j] = __builtin_amdgcn_mfma_f32_16x16x32_bf16(af[i], bfr[j], acc[4 + i][j], 0, 0, 0);
    __builtin_amdgcn_s_setprio(0);

    // ---- phase 2: kh=1, mh=0 ----
    STAGE_A(nxt, 1, ktn);
    asm volatile("s_waitcnt vmcnt(6)" ::: "memory");
    __builtin_amdgcn_s_barrier();
    __builtin_amdgcn_sched_barrier(0);
#pragma unroll
    for (int x = 0; x < 4; x++)
      af[x] = *(const bf16x8*)(Ac1 + (size_t)(aRow + x * 16) * 64 + sw16);
#pragma unroll
    for (int x = 0; x < 4; x++)
      bfr[x] = *(const bf16x8*)(Bc1 + (size_t)(bRow + x * 16) * 64 + sw16);
    __builtin_amdgcn_s_setprio(1);
#pragma unroll
    for (int i = 0; i < 4; i++)
#pragma unroll
      for (int j = 0; j < 4; j++)
        acc[i][j] = __builtin_amdgcn_mfma_f32_16x16x32_bf16(af[i], bfr[j], acc[i][j], 0, 0, 0);
    __builtin_amdgcn_s_setprio(0);

    // ---- phase 3: kh=1, mh=1 (reuse bfr) ----
    STAGE_B(nxt, 1, ktn);
#pragma unroll
    for (int x = 0; x < 4; x++)
      af[x] = *(const bf16x8*)(Ac1 + (size_t)(aRow + 64 + x * 16) * 64 + sw16);
    __builtin_amdgcn_s_setprio(1);
#pragma unroll
    for (int i = 0; i < 4; i++)
#pragma unroll
      for (int j = 0; j < 4; j++)
        acc[4 + i][j] = __builtin_amdgcn_mfma_f32_16x16x32_bf16(af[i], bfr[j], acc[4 + i][j], 0, 0, 0);
    __builtin_amdgcn_s_setprio(0);

    __builtin_amdgcn_s_barrier();  // all reads of cur done before anyone stages over it
    __builtin_amdgcn_sched_barrier(0);
  }
#undef AH
#undef BH
#undef STAGE_A
#undef STAGE_B

  // epilogue: D row = t0 + wm*128 + i*16 + quad*4 + r ; col = n0 + wn*64 + j*16 + mb
  if (n0 < kHID) {  // Q: scale by ss[col%192], bf16
#pragma unroll
    for (int j = 0; j < 4; j++) {
      int colj = n0 + wn * 64 + j * 16 + mb;
      float ssv = ssb[colj % kD];
#pragma unroll
      for (int i = 0; i < 8; i++)
#pragma unroll
        for (int r = 0; r < 4; r++) {
          int row = t0 + wm * 128 + i * 16 + quad * 4 + r;
          qbout[(size_t)row * kHID + colj] = (bf16_t)(acc[i][j][r] * ssv);
        }
    }
  } else if (n0 < 2 * kHID) {  // K rows
#pragma unroll
    for (int i = 0; i < 8; i++)
#pragma unroll
      for (int j = 0; j < 4; j++)
#pragma unroll
        for (int r = 0; r < 4; r++) {
          int row = t0 + wm * 128 + i * 16 + quad * 4 + r;
          int col = (n0 - kHID) + wn * 64 + j * 16 + mb;
          kvout[(size_t)row * kHID + col] = (bf16_t)acc[i][j][r];
        }
  } else {  // V transposed: vtws[vcol][row], 4 rows per 8B store
#pragma unroll
    for (int i = 0; i < 8; i++)
#pragma unroll
      for (int j = 0; j < 4; j++) {
        int vcol = (n0 - 2 * kHID) + wn * 64 + j * 16 + mb;
        int row = t0 + wm * 128 + i * 16 + quad * 4;
        bf16x4_t vv;
#pragma unroll
        for (int r = 0; r < 4; r++) vv[r] = (__bf16)acc[i][j][r];
        *(bf16x4_t*)(vtws + (size_t)vcol * kM + row) = vv;
      }
  }
}

// ---------------------------------------------------------------------------
// Kernel 4 (big-ws): MFMA local relative attention — ROUND-4 base with
// EXACTLY ONE change: V read direct global->VGPR (per-4-chunk clamp;
// e0 % 4 == 0 and all batch boundaries are multiples of 4, so each chunk is
// fully-valid-unshifted or fully-masked with p == exact 0). Vt LDS stage
// removed (zero reuse). sf stays direct-global; launch bounds unchanged.
// ---------------------------------------------------------------------------
__global__ __launch_bounds__(256) void attn_mfma(const bf16_t* __restrict__ kvK,
                                                 const bf16_t* __restrict__ vtws,
                                                 const unsigned char* __restrict__ mask,
                                                 const bf16_t* __restrict__ sinbf,
                                                 const bf16_t* __restrict__ qb,
                                                 float* __restrict__ out) {
  const int g = blockIdx.x, b = blockIdx.y, h = blockIdx.z;
  const int tid = threadIdx.x;
  const int lane = tid & 63, wv = tid >> 6;
  const int w = lane & 15, quad = lane >> 4;
  const int tb = g * 48 - 12;
  const int u = g * 4 + wv;

  __shared__ bf16_t Ks[68 * 192];                  // 26112 B, 384B rows, XOR-swz
  __shared__ __align__(16) char scr[4][1280];      // per-wave bdl f32[16][16] / Pl bf16[16][40]
  __shared__ int vld[68];

  float* bdl = (float*)scr[wv];
  bf16_t* Pl = (bf16_t*)scr[wv];

  // --- Q and sins fragments (direct global, issued before staging) ---
  int tq = u * kW + w;
  int qrow = (u < kU && tq < kT) ? (b * kT + tq) : (b * kT);
  const bf16_t* qptr = qb + (size_t)qrow * kHID + h * kD + quad * 8;
  const bf16_t* sptr = sinbf + (size_t)w * kHID + h * kD + quad * 8;
  bf16x8 qf[6], sf[6];
#pragma unroll
  for (int ks = 0; ks < 6; ks++) {
    qf[ks] = *(const bf16x8*)(qptr + ks * 32);
    sf[ks] = *(const bf16x8*)(sptr + ks * 32);
  }

  // --- V direct loads, group A (T=0..5): per-4-chunk clamp ---
  const int e0 = b * kT + tb + wv * kW + quad * 8;
  const int eBt = e0 + 4;
  const int ecA = e0 < 0 ? 0 : (e0 > kM - 4 ? kM - 4 : e0);
  const int ecB = eBt < 0 ? 0 : (eBt > kM - 4 ? kM - 4 : eBt);
  const bf16_t* vbaseA = vtws + (size_t)(h * kD + w) * kM + ecA;
  const bf16_t* vbaseB = vtws + (size_t)(h * kD + w) * kM + ecB;
  bf16x4_t vA0[6], vA1[6], vB0[6], vB1[6];
#pragma unroll
  for (int T = 0; T < 6; T++) {
    vA0[T] = *(const bf16x4_t*)(vbaseA + (size_t)T * 16 * kM);
    vA1[T] = *(const bf16x4_t*)(vbaseB + (size_t)T * 16 * kM);
  }

  // --- validity of block rows ---
  if (tid < 68) {
    int p = tb + tid;
    vld[tid] = (p >= 0 && p < kT && mask[b * kT + p] == 0) ? 1 : 0;
  }

  // --- stage K: 68 rows x 24 chunks = 1632 slots, swizzled source ---
  const char* kvb = (const char*)kvK;
#pragma unroll
  for (int it = 0; it < 7; it++) {
    int i = it * 256 + tid;
    if (i >= 1632) i -= 1632;  // duplicate-redo keeps waves full
    int r = i / 24, cb = (i % 24) * 16;
    int row = b * kT + tb + r;
    row = row < 0 ? 0 : (row > kM - 1 ? kM - 1 : row);
    const char* src = kvb + (size_t)row * 3072 + h * 384 + (cb ^ ((r & 7) << 4));
    load_lds16(src, (char*)Ks + i * 16);
  }
  __syncthreads();

  // --- V direct loads, group B (T=6..11): in flight during QK^T + softmax ---
#pragma unroll
  for (int T = 0; T < 6; T++) {
    vB0[T] = *(const bf16x4_t*)(vbaseA + (size_t)(T + 6) * 16 * kM);
    vB1[T] = *(const bf16x4_t*)(vbaseB + (size_t)(T + 6) * 16 * kM);
  }

  // --- QK^T + position term ---
  f32x4 ac0 = {0.f, 0.f, 0.f, 0.f}, ac1 = {0.f, 0.f, 0.f, 0.f}, bdv = {0.f, 0.f, 0.f, 0.f};
  const int r0 = wv * kW + w;   // A-row for c-tile0 (block-local)
  const int r1 = r0 + 16;       // c-tile1
#pragma unroll
  for (int ks = 0; ks < 6; ks++) {
    int kb = ks * 64 + quad * 16;
    bf16x8 ka0 = *(const bf16x8*)((const char*)Ks + (size_t)r0 * 384 + (kb ^ ((r0 & 7) << 4)));
    bf16x8 ka1 = *(const bf16x8*)((const char*)Ks + (size_t)r1 * 384 + (kb ^ ((r1 & 7) << 4)));
    ac0 = __builtin_amdgcn_mfma_f32_16x16x32_bf16(ka0, qf[ks], ac0, 0, 0, 0);
    ac1 = __builtin_amdgcn_mfma_f32_16x16x32_bf16(ka1, qf[ks], ac1, 0, 0, 0);
    bdv = __builtin_amdgcn_mfma_f32_16x16x32_bf16(sf[ks], qf[ks], bdv, 0, 0, 0);
  }

  // bd (D[f][w]) -> per-wave LDS so same-w lanes can fetch f = c - w
  *(f32x4*)&bdl[w * 16 + quad * 4] = bdv;
  asm volatile("s_waitcnt lgkmcnt(0)" ::: "memory");

  // --- logits (tanh soft-cap, mask) ---
  float l[8];
#pragma unroll
  for (int T = 0; T < 2; T++)
#pragma unroll
    for (int r = 0; r < 4; r++) {
      int c = T * 16 + quad * 4 + r;
      int f = c - w;
      int fr = f < 0 ? 0 : (f > 15 ? 15 : f);
      float a = T ? ac1[r] : ac0[r];
      float bb = bdl[w * 16 + fr];
      bool val = (f >= 0) && (f <= 12) && (c < kC) && (vld[wv * kW + c] != 0);
      float x2 = (a + bb) * 0.04f;
      float ee = __expf(x2);
      float th = (ee - 1.0f) * __builtin_amdgcn_rcpf(ee + 1.0f);
      l[T * 4 + r] = val ? 50.0f * th : -3.4028234663852886e38f;
    }

  // --- softmax across the 4 lanes sharing w ---
  float m = l[0];
#pragma unroll
  for (int k = 1; k < 8; k++) m = fmaxf(m, l[k]);
  m = fmaxf(m, __shfl_xor(m, 16, 64));
  m = fmaxf(m, __shfl_xor(m, 32, 64));
  float e8[8], s = 0.0f;
#pragma unroll
  for (int k = 0; k < 8; k++) { e8[k] = __expf(l[k] - m); s += e8[k]; }
  s += __shfl_xor(s, 16, 64);
  s += __shfl_xor(s, 32, 64);
  float inv = 1.0f / s;

  // --- probs -> bf16 into Pl (c>=24 pad written as exact 0) ---
#pragma unroll
  for (int T = 0; T < 2; T++) {
    bf16x4_t pk;
#pragma unroll
    for (int r = 0; r < 4; r++) {
      int c = T * 16 + quad * 4 + r;
      float p = (c < kC) ? e8[T * 4 + r] * inv : 0.0f;
      pk[r] = (__bf16)p;
    }
    *(bf16x4_t*)&Pl[w * 40 + T * 16 + quad * 4] = pk;
  }
  asm volatile("s_waitcnt lgkmcnt(0)" ::: "memory");
  __builtin_amdgcn_sched_barrier(0);

  // --- PV: D[w][d] = mfma(P, V-direct) per 16-col d-tile ---
  bf16x8 pa = *(const bf16x8*)&Pl[w * 40 + quad * 8];
  const bool uok = (u < kU);
#pragma unroll
  for (int T = 0; T < 12; T++) {
    bf16x4_t v0 = (T < 6) ? vA0[T] : vB0[T - 6];
    bf16x4_t v1 = (T < 6) ? vA1[T] : vB1[T - 6];
    bf16x8 vf;
#pragma unroll
    for (int e2 = 0; e2 < 4; e2++) { vf[e2] = v0[e2]; vf[e2 + 4] = v1[e2]; }
    f32x4 oz = {0.f, 0.f, 0.f, 0.f};
    oz = __builtin_amdgcn_mfma_f32_16x16x32_bf16(pa, vf, oz, 0, 0, 0);
    if (uok) {
#pragma unroll
      for (int r = 0; r < 4; r++) {
        int wr = quad * 4 + r;
        int t = u * kW + wr;
        if (wr < kW && t < kT)
          out[((size_t)(b * kT + t)) * kHID + h * kD + T * 16 + w] = oz[r];
      }
    }
  }
}

// ---------------------------------------------------------------------------
// Kernel 4 (fallback, small ws): round-1 scalar attention (unchanged).
// ---------------------------------------------------------------------------
__global__ __launch_bounds__(256) void attn_kernel(const bf16_t* __restrict__ kv,
                                                   const unsigned char* __restrict__ mask,
                                                   const float* __restrict__ sinb,
                                                   const float* __restrict__ pds,
                                                   float* __restrict__ out) {
  const int u = blockIdx.x, b = blockIdx.y, h = blockIdx.z;
  const int tid = threadIdx.x;

  __shared__ float qs[kW][kD + 1];
  __shared__ float ks[kC][kD + 1];
  __shared__ float vs[kC][kD + 1];
  __shared__ float sins[kF][kD + 1];
  __shared__ float lg[kW][kC + 1];
  __shared__ float ss[kD];
  __shared__ int validc[kC];

  if (tid < kD) {
    float p = pds[tid];
    float sp = log1pf(expf(p));
    ss[tid] = (1.0f / (sqrtf(192.0f) * logf(2.0f))) * sp;
  }
  if (tid < kC) {
    int p = u * kW + tid - 12;
    validc[tid] = (p >= 0 && p < kT && mask[b * kT + p] == 0) ? 1 : 0;
  }
  __syncthreads();

  for (int i = tid; i < kW * kD; i += 256) {
    int w = i / kD, d = i % kD;
    int t = u * kW + w;
    float v = 0.0f;
    if (t < kT) v = out[((size_t)(b * kT + t)) * kHID + h * kD + d] * ss[d];
    qs[w][d] = v;
  }
  for (int i = tid; i < kC * kD; i += 256) {
    int c = i / kD, d = i % kD;
    int p = u * kW + c - 12;
    float kval = 0.0f, vval = 0.0f;
    if (p >= 0 && p < kT) {
      size_t base = (size_t)(b * kT + p) * kKV;
      kval = (float)kv[base + h * kD + d];
      vval = (float)kv[base + kHID + h * kD + d];
    }
    ks[c][d] = kval;
    vs[c][d] = vval;
  }
  for (int i = tid; i < kF * kD; i += 256) {
    int f = i / kD, d = i % kD;
    sins[f][d] = sinb[f * kHID + h * kD + d];
  }
  __syncthreads();

  for (int i = tid; i < kW * kC; i += 256) {
    int w = i / kC, c = i % kC;
    float l = -3.4028234663852886e38f;
    int f = c - w;
    if (f >= 0 && f <= 12 && validc[c]) {
      float ac = 0.0f, bd = 0.0f;
      for (int d = 0; d < kD; d++) {
        float q = qs[w][d];
        ac += q * ks[c][d];
        bd += q * sins[f][d];
      }
      l = tanhf((ac + bd) * (1.0f / 50.0f)) * 50.0f;
    }
    lg[w][c] = l;
  }
  __syncthreads();

  if (tid < kW) {
    float m = -3.4028234663852886e38f;
#pragma unroll
    for (int c = 0; c < kC; c++) m = fmaxf(m, lg[tid][c]);
    float e[kC];
    float s = 0.0f;
#pragma unroll
    for (int c = 0; c < kC; c++) {
      float ex = expf(lg[tid][c] - m);
      e[c] = ex;
      s += ex;
    }
    float inv = 1.0f / s;
#pragma unroll
    for (int c = 0; c < kC; c++) lg[tid][c] = e[c] * inv;
  }
  __syncthreads();

  for (int i = tid; i < kW * kD; i += 256) {
    int w = i / kD, d = i % kD;
    int t = u * kW + w;
    if (t >= kT) continue;
    float acc = 0.0f;
#pragma unroll
    for (int c = 0; c < 13; c++) acc += lg[w][w + c] * vs[w + c][d];
    out[((size_t)(b * kT + t)) * kHID + h * kD + d] = acc;
  }
}

// ---------------------------------------------------------------------------
extern "C" void kernel_launch(void* const* d_in, const int* in_sizes, int n_in,
                              void* d_out, int out_size, void* d_ws, size_t ws_size,
                              hipStream_t stream) {
  if (ws_size < kWsNeedSmall) return;  // beacon: absmax == 3.92 means ws too small

  const float* hs = (const float*)d_in[0];
  const unsigned char* mask = (const unsigned char*)d_in[1];
  const float* wq = (const float*)d_in[2];
  const float* wk = (const float*)d_in[3];
  const float* wv = (const float*)d_in[4];
  const float* wpos = (const float*)d_in[5];
  const float* pds = (const float*)d_in[6];
  float* out = (float*)d_out;

  char* ws = (char*)d_ws;
  bf16_t* kvK = (bf16_t*)ws;
  bf16_t* vtws = (bf16_t*)(ws + kVtOff);
  bf16_t* wt = (bf16_t*)(ws + kWtOff);
  float* sinb = (float*)(ws + kSinOff);
  bf16_t* sinbf = (bf16_t*)(ws + kSinBfOff);
  float* ssb = (float*)(ws + kSsOff);
  bf16_t* hsb = (bf16_t*)(ws + kHsbOff);
  bf16_t* qb = (bf16_t*)(ws + kQbOff);

  const bool big = ws_size >= kWsNeedBig;

  // one-time opt-in for 128 KiB dynamic LDS; fall back to 128^2 GEMM if denied
  static int g_big_lds = -1;
  if (g_big_lds < 0) {
    g_big_lds = (hipFuncSetAttribute((const void*)gemm256,
                                     hipFuncAttributeMaxDynamicSharedMemorySize,
                                     131072) == hipSuccess) ? 1 : 0;
  }

  transpose_w<<<dim3(48, 48, 3), dim3(32, 8), 0, stream>>>(wq, wk, wv, wt);
  convert_hs<<<dim3(2048), 256, 0, stream>>>(hs, hsb);
  compute_ss<<<1, 192, 0, stream>>>(pds, ssb);

  if (big) {
    float* sinp = (float*)d_out;  // scratch; overwritten later by attn
    sinemb_part<<<dim3(6, 12), 256, 0, stream>>>(wpos, sinp);
    sinemb_reduce<<<dim3(78), 256, 0, stream>>>(sinp, sinb, sinbf);
    bool ran256 = false;
    if (g_big_lds) {
      (void)hipGetLastError();  // clear stale error state
      gemm256<<<dim3(kNQKV / 256, kM / 256), 512, 131072, stream>>>(
          hsb, wt, kvK, vtws, qb, ssb);
      if (hipGetLastError() == hipSuccess) {
        ran256 = true;
      } else {
        g_big_lds = 0;  // don't retry the failing config
      }
    }
    if (!ran256) {
      gemm_qkv_t<1><<<dim3(kNQKV / 128, kM / 128), 256, 0, stream>>>(
          hsb, wt, nullptr, kvK, vtws, qb, ssb);
    }
    attn_mfma<<<dim3(86, kB, kH), 256, 0, stream>>>(kvK, vtws, mask, sinbf, qb, out);
  } else {
    sinemb_kernel<<<dim3(6, 13), 256, 0, stream>>>(wpos, sinb, sinbf);
    gemm_qkv_t<0><<<dim3(kNQKV / 128, kM / 128), 256, 0, stream>>>(
        hsb, wt, out, kvK, nullptr, nullptr, nullptr);
    attn_kernel<<<dim3(kU, kB, kH), 256, 0, stream>>>(kvK, mask, sinb, pds, out);
  }
}